// Round 10
// baseline (417.125 us; speedup 1.0000x reference)
//
#include <hip/hip_runtime.h>
#include <hip/hip_bf16.h>

// Problem constants
#define BB 2
#define CC 256
#define HH 96
#define WW 96
#define HWP (HH*WW)        // 9216
#define NTOT (BB*HWP)      // 18432 flattened (b,p)
#define K1 2304            // 256*9, GEMM K for both convs
#define NKT 36             // K1/64 k-steps
#define KHS 18             // k-steps per split-K half (gemm2)

// d_out layout: logits[2,1,96,96], bbox[2,4,96,96], shape[2,2,96,96], loc[2,1,96,96]
#define OUT_LOGITS 0
#define OUT_BBOX   (2*1*HWP)
#define OUT_SHAPE  (OUT_BBOX + 2*4*HWP)
#define OUT_LOC    (OUT_SHAPE + 2*2*HWP)

typedef __attribute__((ext_vector_type(8))) short short8v;   // 8 bf16 (4 VGPRs)
typedef __attribute__((ext_vector_type(4))) float f32x4;

typedef const __attribute__((address_space(1))) void* gptr_t;
typedef __attribute__((address_space(3))) void* lptr_t;
#define GLOAD16(g, l) __builtin_amdgcn_global_load_lds((gptr_t)(g), (lptr_t)(l), 16, 0, 0)

__device__ __forceinline__ float bf2f(unsigned short u) {
    return __uint_as_float(((unsigned)u) << 16);
}
__device__ __forceinline__ unsigned short f2bf(float f) {
    unsigned u = __float_as_uint(f);
    u += 0x7FFFu + ((u >> 16) & 1u);           // round-to-nearest-even
    return (unsigned short)(u >> 16);
}

// ------- prep: weights -> bf16, BOTH in k = kk*256+ci order; zero page ------
__global__ __launch_bounds__(256) void prep_kernel(
    const float* __restrict__ conv_w, const float* __restrict__ adapt_w,
    unsigned short* __restrict__ W1, unsigned short* __restrict__ W2,
    unsigned short* __restrict__ zp)
{
    const int t = blockIdx.x * 256 + threadIdx.x;
    if (t < 1024) zp[t] = 0;                    // zero page (ws is re-poisoned!)
    if (t < CC * K1) {
        const int co = t / K1, r = t % K1;
        const int kk = r >> 8, ci = r & 255;    // k = kk*256+ci
        W1[t] = f2bf(conv_w[co * K1 + ci * 9 + kk]);
        W2[t] = f2bf(adapt_w[co * K1 + ci * 9 + kk]);
    }
}

// ------------- transpose feature [b][c][p] fp32 -> f_cf [b][p][c] bf16 ------
// grid (144, 4, 2): channel-group split across blockIdx.y (pure permutation).
__global__ __launch_bounds__(256) void transpose_kernel(
    const float* __restrict__ f, unsigned short* __restrict__ fcf)
{
    __shared__ unsigned short tile[64][66];     // +2 pad: conflict-free col reads
    const int p0 = blockIdx.x * 64;
    const int cc = blockIdx.y;
    const int b  = blockIdx.z;
    const int tx = threadIdx.x & 63, ty = threadIdx.x >> 6;
#pragma unroll
    for (int ii = 0; ii < 16; ii++) {
        const int cl = ii * 4 + ty;
        tile[cl][tx] = f2bf(f[((size_t)b * CC + cc * 64 + cl) * HWP + p0 + tx]);
    }
    __syncthreads();
#pragma unroll
    for (int ii = 0; ii < 16; ii++) {
        const int pl = ii * 4 + ty;
        fcf[((size_t)(b * HWP + p0 + pl)) * CC + cc * 64 + tx] = tile[tx][pl];
    }
}

// --------- GEMM1: t = relu(W1 x im2col + bias), M=128 x N=32, BK=64 ---------
// Wave w owns rows [w*32, w*32+32). A: 4 GLOAD16/thread (slot=kc*128+row).
// B: 1 GLOAD16/thread (slot=kc*32+row, implicit im2col). Math verbatim R9.
__global__ __launch_bounds__(256) void gemm1_kernel(
    const unsigned short* __restrict__ W1, const unsigned short* __restrict__ fcf,
    const float* __restrict__ bias, const unsigned short* __restrict__ zp,
    unsigned short* __restrict__ tcf)
{
    __shared__ short As[8192];                  // 128 rows x 64 k = 16 KB
    __shared__ short Bs[2048];                  // 32 rows x 64 k = 4 KB
    const int tid  = threadIdx.x;
    const int lane = tid & 63, w = tid >> 6;
    const int quad = lane >> 4, r15 = lane & 15;
    const int n0  = blockIdx.x * 32;            // flattened (b,p); 9216%32==0
    const int co0 = blockIdx.y * 128;

    // B staging geometry: slot = w*64 + lane -> (kc = w*2 + (lane>>5), row = lane&31)
    const int brow = lane & 31;
    const int bkc  = w * 2 + (lane >> 5);
    const int nb = n0 + brow;
    const int b  = nb / HWP;
    const int p  = nb - b * HWP;
    const int y = p / WW, x = p % WW;
    const unsigned short* fb = fcf + (size_t)b * HWP * CC;

    f32x4 acc[2][2];
#pragma unroll
    for (int i = 0; i < 2; i++)
#pragma unroll
        for (int j = 0; j < 2; j++) acc[i][j] = (f32x4){0.f, 0.f, 0.f, 0.f};

    for (int kt = 0; kt < NKT; kt++) {
        const int k0 = kt * 64;
#pragma unroll
        for (int i = 0; i < 4; i++) {           // A: 4 chunks/thread
            const int kc    = w * 2 + (i >> 1);
            const int row   = ((i & 1) << 6) + lane;
            const int sbase = w * 256 + i * 64;
            GLOAD16(W1 + (size_t)(co0 + row) * K1 + k0 + kc * 8, &As[sbase * 8]);
        }
        {                                       // B: 1 chunk/thread, implicit im2col
            const int k   = k0 + bkc * 8;
            const int kk  = k >> 8;
            const int ci0 = k & 255;
            const int yy = y + kk / 3 - 1, xx = x + kk % 3 - 1;
            const bool ok = (yy >= 0) && (yy < HH) && (xx >= 0) && (xx < WW);
            const unsigned short* gb = ok
                ? fb + (size_t)(yy * WW + xx) * CC + ci0
                : zp;
            GLOAD16(gb, &Bs[(w * 64) * 8]);     // uniform base; +lane*16 via DMA
        }
        __syncthreads();
#pragma unroll
        for (int ks = 0; ks < 2; ks++) {
            short8v a[2], bf[2];
#pragma unroll
            for (int i = 0; i < 2; i++)
                a[i] = *(const short8v*)&As[(((ks * 4 + quad) * 128) + w * 32 + i * 16 + r15) * 8];
#pragma unroll
            for (int j = 0; j < 2; j++)
                bf[j] = *(const short8v*)&Bs[(((ks * 4 + quad) * 32) + j * 16 + r15) * 8];
#pragma unroll
            for (int i = 0; i < 2; i++)
#pragma unroll
                for (int j = 0; j < 2; j++)
                    acc[i][j] = __builtin_amdgcn_mfma_f32_16x16x32_bf16(a[i], bf[j], acc[i][j], 0, 0, 0);
        }
        __syncthreads();
    }
    // epilogue: bias + relu -> t_cf[n][c] bf16 (C/D map: col=lane&15, row=quad*4+reg)
#pragma unroll
    for (int i = 0; i < 2; i++) {
        const int m = co0 + w * 32 + i * 16 + quad * 4;
        const float b0 = bias[m], b1 = bias[m + 1], b2 = bias[m + 2], b3 = bias[m + 3];
#pragma unroll
        for (int j = 0; j < 2; j++) {
            const int n = n0 + j * 16 + r15;
            ushort4 st;
            st.x = f2bf(fmaxf(acc[i][j][0] + b0, 0.f));
            st.y = f2bf(fmaxf(acc[i][j][1] + b1, 0.f));
            st.z = f2bf(fmaxf(acc[i][j][2] + b2, 0.f));
            st.w = f2bf(fmaxf(acc[i][j][3] + b3, 0.f));
            *(ushort4*)(tcf + (size_t)n * CC + m) = st;
        }
    }
}

// ---- heads1 (R9-verbatim): loc/shape -> out; (s0,s1) per pixel -> ws -------
__global__ __launch_bounds__(64) void heads1_kernel(
    const unsigned short* __restrict__ tcf,
    const float* __restrict__ loc_w, const float* __restrict__ loc_b,
    const float* __restrict__ shape_w, const float* __restrict__ shape_b,
    float* __restrict__ out, float* __restrict__ s0s1)
{
    const int n = blockIdx.x * 64 + threadIdx.x;
    const int b = n / HWP, p = n - b * HWP;
    const unsigned short* row = tcf + (size_t)n * CC;
    float aloc = 0.f, s0 = 0.f, s1 = 0.f;
    for (int c = 0; c < CC; c += 8) {
        short8v v = *(const short8v*)&row[c];
#pragma unroll
        for (int k = 0; k < 8; k++) {
            const float fv = bf2f((unsigned short)v[k]);
            aloc = fmaf(loc_w[c + k], fv, aloc);
            s0   = fmaf(shape_w[c + k], fv, s0);
            s1   = fmaf(shape_w[CC + c + k], fv, s1);
        }
    }
    aloc += loc_b[0]; s0 += shape_b[0]; s1 += shape_b[1];
    out[OUT_LOC + n] = aloc;
    out[OUT_SHAPE + (b * 2 + 0) * HWP + p] = s0;
    out[OUT_SHAPE + (b * 2 + 1) * HWP + p] = s1;
    *(float2*)&s0s1[2 * n] = make_float2(s0, s1);
}

// ---- fused GEMM2, split-K=2, M=256 x N=16: partial = W2[:,Kh] x B(Kh) ------
// Block (n0, kh) does k-steps [18kh, 18kh+18). Sampling math verbatim R9;
// threads<128 sample (pr=tid>>3 < 16, kc=tid&7); all threads stage A + MFMA.
// Output: fp32 partials, NO relu, to disjoint pta[kh].
__global__ __launch_bounds__(256) void gemm2_fused_kernel(
    const unsigned short* __restrict__ W2, const unsigned short* __restrict__ tcf,
    const float* __restrict__ s0s1, const float* __restrict__ offset_w,
    float* __restrict__ pta0, float* __restrict__ pta1)
{
    __shared__ short As[16384];                 // 8 kc-chunks x 256 rows x 16B = 32 KB
    __shared__ short Bs[16 * 9 * 8];            // padded layout, 2.3 KB
    const int tid  = threadIdx.x;
    const int lane = tid & 63, w = tid >> 6;
    const int quad = lane >> 4, r15 = lane & 15;
    const int n0  = blockIdx.x * 16;
    const int kh  = blockIdx.y;                 // split-K half

    // sampler mapping: threads<128 -> (pixel pr, 8-ch chunk kc)
    const int pr = tid >> 3, kc = tid & 7;
    const bool samp = tid < 128;                // pr < 16
    float2 s01 = make_float2(0.f, 0.f);
    int y = 0, x = 0;
    const unsigned short* tb = tcf;
    if (samp) {
        const int nb = n0 + pr;
        const int b  = nb / HWP;
        const int p  = nb - b * HWP;
        y = p / WW; x = p % WW;
        s01 = *(const float2*)&s0s1[2 * nb];
        tb = tcf + (size_t)b * HWP * CC;
    }

    f32x4 acc[4];
#pragma unroll
    for (int i = 0; i < 4; i++) acc[i] = (f32x4){0.f, 0.f, 0.f, 0.f};

    for (int kt = kh * KHS; kt < kh * KHS + KHS; kt++) {
        const int k0 = kt * 64;
        const int kk = kt >> 2, g = kt & 3;
        // A: wave w stages kc-chunks {2w, 2w+1} x all 256 rows (slot = kc*256+row)
#pragma unroll
        for (int i = 0; i < 8; i++) {
            const int kca   = w * 2 + (i >> 2);
            const int rr    = (i & 3) * 64;          // + lane via DMA
            const int sbase = kca * 256 + rr;
            GLOAD16(W2 + (size_t)(rr + lane) * K1 + k0 + kca * 8, &As[sbase * 8]);
        }
        // B: bilinear sample of 8 channels (R9-verbatim math), threads<128
        if (samp) {
            const int o_dy = (g * 9 + kk) * 2, o_dx = o_dy + 1;
            const float dy = fmaf(offset_w[o_dy * 2], s01.x, offset_w[o_dy * 2 + 1] * s01.y);
            const float dx = fmaf(offset_w[o_dx * 2], s01.x, offset_w[o_dx * 2 + 1] * s01.y);
            const float py = (float)(y + kk / 3 - 1) + dy;
            const float px = (float)(x + kk % 3 - 1) + dx;
            const float y0f = floorf(py), x0f = floorf(px);
            const float wy = py - y0f, wx = px - x0f;
            const int y0 = (int)y0f, x0 = (int)x0f;
            const int y1 = y0 + 1, x1 = x0 + 1;
            const bool vy0 = (y0 >= 0) && (y0 < HH), vy1 = (y1 >= 0) && (y1 < HH);
            const bool vx0 = (x0 >= 0) && (x0 < WW), vx1 = (x1 >= 0) && (x1 < WW);
            const int y0c = min(max(y0, 0), HH - 1), y1c = min(max(y1, 0), HH - 1);
            const int x0c = min(max(x0, 0), WW - 1), x1c = min(max(x1, 0), WW - 1);
            const float w00 = (vy0 && vx0) ? (1.f - wy) * (1.f - wx) : 0.f;
            const float w01 = (vy0 && vx1) ? (1.f - wy) * wx         : 0.f;
            const float w10 = (vy1 && vx0) ? wy * (1.f - wx)         : 0.f;
            const float w11 = (vy1 && vx1) ? wy * wx                 : 0.f;
            const int ch = g * 64 + kc * 8;
            const short8v v00 = *(const short8v*)(tb + (size_t)(y0c * WW + x0c) * CC + ch);
            const short8v v01 = *(const short8v*)(tb + (size_t)(y0c * WW + x1c) * CC + ch);
            const short8v v10 = *(const short8v*)(tb + (size_t)(y1c * WW + x0c) * CC + ch);
            const short8v v11 = *(const short8v*)(tb + (size_t)(y1c * WW + x1c) * CC + ch);
            short8v r;
#pragma unroll
            for (int e = 0; e < 8; e++) {
                float val = w00 * bf2f((unsigned short)v00[e]);
                val = fmaf(w01, bf2f((unsigned short)v01[e]), val);
                val = fmaf(w10, bf2f((unsigned short)v10[e]), val);
                val = fmaf(w11, bf2f((unsigned short)v11[e]), val);
                r[e] = (short)f2bf(val);
            }
            *(short8v*)&Bs[(pr * 9 + kc) * 8] = r;
        }
        __syncthreads();
#pragma unroll
        for (int ks = 0; ks < 2; ks++) {
            short8v a[4], bf;
#pragma unroll
            for (int i = 0; i < 4; i++)
                a[i] = *(const short8v*)&As[(((ks * 4 + quad) * 256) + w * 64 + i * 16 + r15) * 8];
            bf = *(const short8v*)&Bs[(r15 * 9 + ks * 4 + quad) * 8];
#pragma unroll
            for (int i = 0; i < 4; i++)
                acc[i] = __builtin_amdgcn_mfma_f32_16x16x32_bf16(a[i], bf, acc[i], 0, 0, 0);
        }
        __syncthreads();
    }
    // epilogue: fp32 partial, no relu (C/D map: col=lane&15, row=quad*4+reg)
    float* pta = kh ? pta1 : pta0;
    const int n = n0 + r15;
#pragma unroll
    for (int i = 0; i < 4; i++) {
        const int m = w * 64 + i * 16 + quad * 4;
        *(f32x4*)(pta + (size_t)n * CC + m) = acc[i];
    }
}

// ---- heads2 (R9-verbatim): cls/bbox from relu(pta0+pta1), fp32 -------------
__global__ __launch_bounds__(64) void heads2_kernel(
    const float* __restrict__ pta0, const float* __restrict__ pta1,
    const float* __restrict__ cls_w, const float* __restrict__ cls_b,
    const float* __restrict__ bbox_w, const float* __restrict__ bbox_b,
    float* __restrict__ out)
{
    const int n = blockIdx.x * 64 + threadIdx.x;
    const int b = n / HWP, p = n - b * HWP;
    const float* r0 = pta0 + (size_t)n * CC;
    const float* r1 = pta1 + (size_t)n * CC;
    float ac = 0.f, a0 = 0.f, a1 = 0.f, a2 = 0.f, a3 = 0.f;
    for (int c = 0; c < CC; c += 4) {
        const float4 u = *(const float4*)&r0[c];
        const float4 v = *(const float4*)&r1[c];
        float fv[4];
        fv[0] = fmaxf(u.x + v.x, 0.f);
        fv[1] = fmaxf(u.y + v.y, 0.f);
        fv[2] = fmaxf(u.z + v.z, 0.f);
        fv[3] = fmaxf(u.w + v.w, 0.f);
#pragma unroll
        for (int k = 0; k < 4; k++) {
            ac = fmaf(cls_w[c + k], fv[k], ac);
            a0 = fmaf(bbox_w[c + k], fv[k], a0);
            a1 = fmaf(bbox_w[CC + c + k], fv[k], a1);
            a2 = fmaf(bbox_w[2 * CC + c + k], fv[k], a2);
            a3 = fmaf(bbox_w[3 * CC + c + k], fv[k], a3);
        }
    }
    out[OUT_LOGITS + n] = ac + cls_b[0];
    out[OUT_BBOX + (b * 4 + 0) * HWP + p] = a0 + bbox_b[0];
    out[OUT_BBOX + (b * 4 + 1) * HWP + p] = a1 + bbox_b[1];
    out[OUT_BBOX + (b * 4 + 2) * HWP + p] = a2 + bbox_b[2];
    out[OUT_BBOX + (b * 4 + 3) * HWP + p] = a3 + bbox_b[3];
}

// ----------------------------------------------------------------------------
extern "C" void kernel_launch(void* const* d_in, const int* in_sizes, int n_in,
                              void* d_out, int out_size, void* d_ws, size_t ws_size,
                              hipStream_t stream)
{
    const float* feature  = (const float*)d_in[0];
    const float* conv_w   = (const float*)d_in[1];
    const float* conv_b   = (const float*)d_in[2];
    const float* loc_w    = (const float*)d_in[3];
    const float* loc_b    = (const float*)d_in[4];
    const float* shape_w  = (const float*)d_in[5];
    const float* shape_b  = (const float*)d_in[6];
    const float* offset_w = (const float*)d_in[7];
    const float* adapt_w  = (const float*)d_in[8];
    const float* cls_w    = (const float*)d_in[9];
    const float* cls_b    = (const float*)d_in[10];
    const float* bbox_w   = (const float*)d_in[11];
    const float* bbox_b   = (const float*)d_in[12];
    float* out = (float*)d_out;

    // workspace partition (~59 MB)
    float*          s0s1 = (float*)d_ws;                           // NTOT float2
    unsigned short* tcf  = (unsigned short*)(s0s1 + 2 * NTOT);     // NTOT*CC bf16
    unsigned short* fcf  = tcf + (size_t)NTOT * CC;                // NTOT*CC bf16
    unsigned short* W1   = fcf + (size_t)NTOT * CC;                // CC*K1 bf16
    unsigned short* W2   = W1 + (size_t)CC * K1;                   // CC*K1 bf16
    unsigned short* zp   = W2 + (size_t)CC * K1;                   // 1024 zeros
    float*          pta0 = (float*)(zp + 1024);                    // NTOT*CC fp32
    float*          pta1 = pta0 + (size_t)NTOT * CC;               // NTOT*CC fp32

    prep_kernel<<<(CC * K1 + 255) / 256, 256, 0, stream>>>(conv_w, adapt_w, W1, W2, zp);
    transpose_kernel<<<dim3(HWP / 64, 4, BB), 256, 0, stream>>>(feature, fcf);
    gemm1_kernel<<<dim3(NTOT / 32, 2), 256, 0, stream>>>(W1, fcf, conv_b, zp, tcf);
    heads1_kernel<<<dim3(NTOT / 64), 64, 0, stream>>>(
        tcf, loc_w, loc_b, shape_w, shape_b, out, s0s1);
    gemm2_fused_kernel<<<dim3(NTOT / 16, 2), 256, 0, stream>>>(
        W2, tcf, s0s1, offset_w, pta0, pta1);
    heads2_kernel<<<dim3(NTOT / 64), 64, 0, stream>>>(
        pta0, pta1, cls_w, cls_b, bbox_w, bbox_b, out);
}

// Round 11
// 297.084 us; speedup vs baseline: 1.4041x; 1.4041x over previous
//
#include <hip/hip_runtime.h>
#include <hip/hip_bf16.h>

// Problem constants
#define BB 2
#define CC 256
#define HH 96
#define WW 96
#define HWP (HH*WW)        // 9216
#define NTOT (BB*HWP)      // 18432 flattened (b,p)
#define K1 2304            // 256*9, GEMM K for both convs
#define NKT 36             // K1/64 k-steps
#define KHS 18             // k-steps per split-K half (gemm2)

// d_out layout: logits[2,1,96,96], bbox[2,4,96,96], shape[2,2,96,96], loc[2,1,96,96]
#define OUT_LOGITS 0
#define OUT_BBOX   (2*1*HWP)
#define OUT_SHAPE  (OUT_BBOX + 2*4*HWP)
#define OUT_LOC    (OUT_SHAPE + 2*2*HWP)

typedef __attribute__((ext_vector_type(8))) short short8v;   // 8 bf16 (4 VGPRs)
typedef __attribute__((ext_vector_type(4))) float f32x4;

typedef const __attribute__((address_space(1))) void* gptr_t;
typedef __attribute__((address_space(3))) void* lptr_t;
#define GLOAD16(g, l) __builtin_amdgcn_global_load_lds((gptr_t)(g), (lptr_t)(l), 16, 0, 0)

__device__ __forceinline__ float bf2f(unsigned short u) {
    return __uint_as_float(((unsigned)u) << 16);
}
__device__ __forceinline__ unsigned short f2bf(float f) {
    unsigned u = __float_as_uint(f);
    u += 0x7FFFu + ((u >> 16) & 1u);           // round-to-nearest-even
    return (unsigned short)(u >> 16);
}

// ------- prep: weights -> bf16, BOTH in k = kk*256+ci order; zero page ------
__global__ __launch_bounds__(256) void prep_kernel(
    const float* __restrict__ conv_w, const float* __restrict__ adapt_w,
    unsigned short* __restrict__ W1, unsigned short* __restrict__ W2,
    unsigned short* __restrict__ zp)
{
    const int t = blockIdx.x * 256 + threadIdx.x;
    if (t < 1024) zp[t] = 0;                    // zero page (ws is re-poisoned!)
    if (t < CC * K1) {
        const int co = t / K1, r = t % K1;
        const int kk = r >> 8, ci = r & 255;    // k = kk*256+ci
        W1[t] = f2bf(conv_w[co * K1 + ci * 9 + kk]);
        W2[t] = f2bf(adapt_w[co * K1 + ci * 9 + kk]);
    }
}

// ------------- transpose feature [b][c][p] fp32 -> f_cf [b][p][c] bf16 ------
// grid (144, 4, 2): channel-group split across blockIdx.y (pure permutation).
__global__ __launch_bounds__(256) void transpose_kernel(
    const float* __restrict__ f, unsigned short* __restrict__ fcf)
{
    __shared__ unsigned short tile[64][66];     // +2 pad: conflict-free col reads
    const int p0 = blockIdx.x * 64;
    const int cc = blockIdx.y;
    const int b  = blockIdx.z;
    const int tx = threadIdx.x & 63, ty = threadIdx.x >> 6;
#pragma unroll
    for (int ii = 0; ii < 16; ii++) {
        const int cl = ii * 4 + ty;
        tile[cl][tx] = f2bf(f[((size_t)b * CC + cc * 64 + cl) * HWP + p0 + tx]);
    }
    __syncthreads();
#pragma unroll
    for (int ii = 0; ii < 16; ii++) {
        const int pl = ii * 4 + ty;
        fcf[((size_t)(b * HWP + p0 + pl)) * CC + cc * 64 + tx] = tile[tx][pl];
    }
}

// --------- GEMM1 (R9-verbatim, passed): t = relu(W1 x im2col + bias) --------
// 128M x 64N tile, BK=64, 4 waves (2x2), 16x16x32 MFMA, global_load_lds.
__global__ __launch_bounds__(256) void gemm1_kernel(
    const unsigned short* __restrict__ W1, const unsigned short* __restrict__ fcf,
    const float* __restrict__ bias, const unsigned short* __restrict__ zp,
    unsigned short* __restrict__ tcf)
{
    __shared__ short As[8192];                  // 128 rows x 64 k = 16 KB
    __shared__ short Bs[4096];                  // 64 rows x 64 k = 8 KB
    const int tid  = threadIdx.x;
    const int lane = tid & 63, w = tid >> 6;
    const int quad = lane >> 4, r15 = lane & 15;
    const int n0  = blockIdx.x * 64;            // flattened (b,p); 9216%64==0
    const int co0 = blockIdx.y * 128;
    const int wm = w >> 1, wn = w & 1;

    const int nb = n0 + lane;
    const int b  = nb / HWP;
    const int p  = nb - b * HWP;
    const int y = p / WW, x = p % WW;

    f32x4 acc[4][2];
#pragma unroll
    for (int i = 0; i < 4; i++)
#pragma unroll
        for (int j = 0; j < 2; j++) acc[i][j] = (f32x4){0.f, 0.f, 0.f, 0.f};

    for (int kt = 0; kt < NKT; kt++) {
        const int k0 = kt * 64;
#pragma unroll
        for (int i = 0; i < 4; i++) {           // A: 4 chunks/thread
            const int kc    = w * 2 + (i >> 1);
            const int row   = ((i & 1) << 6) + lane;
            const int sbase = w * 256 + i * 64;
            GLOAD16(W1 + (size_t)(co0 + row) * K1 + k0 + kc * 8, &As[sbase * 8]);
        }
#pragma unroll
        for (int i = 0; i < 2; i++) {           // B: 2 chunks/thread, implicit im2col
            const int kc    = w * 2 + i;
            const int sbase = w * 128 + i * 64;
            const int k   = k0 + kc * 8;
            const int kk  = k >> 8;
            const int ci0 = k & 255;
            const int yy = y + kk / 3 - 1, xx = x + kk % 3 - 1;
            const bool ok = (yy >= 0) && (yy < HH) && (xx >= 0) && (xx < WW);
            const unsigned short* gb = ok
                ? fcf + ((size_t)(b * HWP + yy * WW + xx)) * CC + ci0
                : zp;
            GLOAD16(gb, &Bs[sbase * 8]);
        }
        __syncthreads();
#pragma unroll
        for (int ks = 0; ks < 2; ks++) {
            short8v a[4], bf[2];
#pragma unroll
            for (int i = 0; i < 4; i++)
                a[i] = *(const short8v*)&As[(((ks * 4 + quad) * 128) + wm * 64 + i * 16 + r15) * 8];
#pragma unroll
            for (int j = 0; j < 2; j++)
                bf[j] = *(const short8v*)&Bs[(((ks * 4 + quad) * 64) + wn * 32 + j * 16 + r15) * 8];
#pragma unroll
            for (int i = 0; i < 4; i++)
#pragma unroll
                for (int j = 0; j < 2; j++)
                    acc[i][j] = __builtin_amdgcn_mfma_f32_16x16x32_bf16(a[i], bf[j], acc[i][j], 0, 0, 0);
        }
        __syncthreads();
    }
    // epilogue: bias + relu -> t_cf[n][c] bf16 (C/D map: col=lane&15, row=quad*4+reg)
#pragma unroll
    for (int i = 0; i < 4; i++) {
        const int m = co0 + wm * 64 + i * 16 + quad * 4;
        const float b0 = bias[m], b1 = bias[m + 1], b2 = bias[m + 2], b3 = bias[m + 3];
#pragma unroll
        for (int j = 0; j < 2; j++) {
            const int n = n0 + wn * 32 + j * 16 + r15;
            ushort4 st;
            st.x = f2bf(fmaxf(acc[i][j][0] + b0, 0.f));
            st.y = f2bf(fmaxf(acc[i][j][1] + b1, 0.f));
            st.z = f2bf(fmaxf(acc[i][j][2] + b2, 0.f));
            st.w = f2bf(fmaxf(acc[i][j][3] + b3, 0.f));
            *(ushort4*)(tcf + (size_t)n * CC + m) = st;
        }
    }
}

// ---- heads1 (R9-verbatim): loc/shape -> out; (s0,s1) per pixel -> ws -------
__global__ __launch_bounds__(64) void heads1_kernel(
    const unsigned short* __restrict__ tcf,
    const float* __restrict__ loc_w, const float* __restrict__ loc_b,
    const float* __restrict__ shape_w, const float* __restrict__ shape_b,
    float* __restrict__ out, float* __restrict__ s0s1)
{
    const int n = blockIdx.x * 64 + threadIdx.x;
    const int b = n / HWP, p = n - b * HWP;
    const unsigned short* row = tcf + (size_t)n * CC;
    float aloc = 0.f, s0 = 0.f, s1 = 0.f;
    for (int c = 0; c < CC; c += 8) {
        short8v v = *(const short8v*)&row[c];
#pragma unroll
        for (int k = 0; k < 8; k++) {
            const float fv = bf2f((unsigned short)v[k]);
            aloc = fmaf(loc_w[c + k], fv, aloc);
            s0   = fmaf(shape_w[c + k], fv, s0);
            s1   = fmaf(shape_w[CC + c + k], fv, s1);
        }
    }
    aloc += loc_b[0]; s0 += shape_b[0]; s1 += shape_b[1];
    out[OUT_LOC + n] = aloc;
    out[OUT_SHAPE + (b * 2 + 0) * HWP + p] = s0;
    out[OUT_SHAPE + (b * 2 + 1) * HWP + p] = s1;
    *(float2*)&s0s1[2 * n] = make_float2(s0, s1);
}

// ---- fused GEMM2, split-K=2, M=256 x N=64: partial = W2[:,Kh] x B(Kh) ------
// Block (n0, kh) does k-steps [18kh, 18kh+18). Sampling math bit-identical to
// R9; each thread samples 2 pixels (pr0=tid>>3, pr1=pr0+32) x 8-ch chunk kc.
// N=64 halves total block-steps vs R9 (the R10 lesson: per-step A-staging is
// the fixed cost; amortize it over more MFMA, not more blocks).
__global__ __launch_bounds__(256) void gemm2_fused_kernel(
    const unsigned short* __restrict__ W2, const unsigned short* __restrict__ tcf,
    const float* __restrict__ s0s1, const float* __restrict__ offset_w,
    float* __restrict__ pta0, float* __restrict__ pta1)
{
    __shared__ short As[16384];                 // 8 kc-chunks x 256 rows x 16B = 32 KB
    __shared__ short Bs[64 * 9 * 8];            // padded layout, 9 KB
    const int tid  = threadIdx.x;
    const int lane = tid & 63, w = tid >> 6;
    const int quad = lane >> 4, r15 = lane & 15;
    const int n0  = blockIdx.x * 64;
    const int kh  = blockIdx.y;                 // split-K half
    const int b   = n0 / HWP;                   // whole block in one batch
    const unsigned short* tb = tcf + (size_t)b * HWP * CC;

    // sampler mapping: thread -> pixels {pr0, pr1}, 8-ch chunk kc
    const int pr0 = tid >> 3, kc = tid & 7;
    int ys[2], xs[2];
    float2 s01s[2];
#pragma unroll
    for (int s = 0; s < 2; s++) {
        const int nb = n0 + pr0 + s * 32;
        const int p  = nb - b * HWP;
        ys[s] = p / WW; xs[s] = p % WW;
        s01s[s] = *(const float2*)&s0s1[2 * nb];
    }

    f32x4 acc[4][4];
#pragma unroll
    for (int i = 0; i < 4; i++)
#pragma unroll
        for (int j = 0; j < 4; j++) acc[i][j] = (f32x4){0.f, 0.f, 0.f, 0.f};

    for (int kt = kh * KHS; kt < kh * KHS + KHS; kt++) {
        const int k0 = kt * 64;
        const int kk = kt >> 2, g = kt & 3;
        // A: wave w stages kc-chunks {2w, 2w+1} x all 256 rows (slot = kc*256+row)
#pragma unroll
        for (int i = 0; i < 8; i++) {
            const int kca   = w * 2 + (i >> 2);
            const int rr    = (i & 3) * 64;          // + lane via DMA
            const int sbase = kca * 256 + rr;
            GLOAD16(W2 + (size_t)(rr + lane) * K1 + k0 + kca * 8, &As[sbase * 8]);
        }
        // B: bilinear sample of 8 channels x 2 pixels (R9-verbatim math)
#pragma unroll
        for (int s = 0; s < 2; s++) {
            const float2 s01 = s01s[s];
            const int y = ys[s], x = xs[s];
            const int o_dy = (g * 9 + kk) * 2, o_dx = o_dy + 1;
            const float dy = fmaf(offset_w[o_dy * 2], s01.x, offset_w[o_dy * 2 + 1] * s01.y);
            const float dx = fmaf(offset_w[o_dx * 2], s01.x, offset_w[o_dx * 2 + 1] * s01.y);
            const float py = (float)(y + kk / 3 - 1) + dy;
            const float px = (float)(x + kk % 3 - 1) + dx;
            const float y0f = floorf(py), x0f = floorf(px);
            const float wy = py - y0f, wx = px - x0f;
            const int y0 = (int)y0f, x0 = (int)x0f;
            const int y1 = y0 + 1, x1 = x0 + 1;
            const bool vy0 = (y0 >= 0) && (y0 < HH), vy1 = (y1 >= 0) && (y1 < HH);
            const bool vx0 = (x0 >= 0) && (x0 < WW), vx1 = (x1 >= 0) && (x1 < WW);
            const int y0c = min(max(y0, 0), HH - 1), y1c = min(max(y1, 0), HH - 1);
            const int x0c = min(max(x0, 0), WW - 1), x1c = min(max(x1, 0), WW - 1);
            const float w00 = (vy0 && vx0) ? (1.f - wy) * (1.f - wx) : 0.f;
            const float w01 = (vy0 && vx1) ? (1.f - wy) * wx         : 0.f;
            const float w10 = (vy1 && vx0) ? wy * (1.f - wx)         : 0.f;
            const float w11 = (vy1 && vx1) ? wy * wx                 : 0.f;
            const int ch = g * 64 + kc * 8;
            const short8v v00 = *(const short8v*)(tb + (size_t)(y0c * WW + x0c) * CC + ch);
            const short8v v01 = *(const short8v*)(tb + (size_t)(y0c * WW + x1c) * CC + ch);
            const short8v v10 = *(const short8v*)(tb + (size_t)(y1c * WW + x0c) * CC + ch);
            const short8v v11 = *(const short8v*)(tb + (size_t)(y1c * WW + x1c) * CC + ch);
            short8v r;
#pragma unroll
            for (int e = 0; e < 8; e++) {
                float val = w00 * bf2f((unsigned short)v00[e]);
                val = fmaf(w01, bf2f((unsigned short)v01[e]), val);
                val = fmaf(w10, bf2f((unsigned short)v10[e]), val);
                val = fmaf(w11, bf2f((unsigned short)v11[e]), val);
                r[e] = (short)f2bf(val);
            }
            *(short8v*)&Bs[((pr0 + s * 32) * 9 + kc) * 8] = r;
        }
        __syncthreads();
#pragma unroll
        for (int ks = 0; ks < 2; ks++) {
            short8v a[4], bf[4];
#pragma unroll
            for (int i = 0; i < 4; i++)
                a[i] = *(const short8v*)&As[(((ks * 4 + quad) * 256) + w * 64 + i * 16 + r15) * 8];
#pragma unroll
            for (int j = 0; j < 4; j++)
                bf[j] = *(const short8v*)&Bs[((j * 16 + r15) * 9 + ks * 4 + quad) * 8];
#pragma unroll
            for (int i = 0; i < 4; i++)
#pragma unroll
                for (int j = 0; j < 4; j++)
                    acc[i][j] = __builtin_amdgcn_mfma_f32_16x16x32_bf16(a[i], bf[j], acc[i][j], 0, 0, 0);
        }
        __syncthreads();
    }
    // epilogue: fp32 partial, no relu (C/D map: col=lane&15, row=quad*4+reg)
    float* pta = kh ? pta1 : pta0;
#pragma unroll
    for (int i = 0; i < 4; i++) {
        const int m = w * 64 + i * 16 + quad * 4;
#pragma unroll
        for (int j = 0; j < 4; j++) {
            const int n = n0 + j * 16 + r15;
            *(f32x4*)(pta + (size_t)n * CC + m) = acc[i][j];
        }
    }
}

// ---- heads2 (R9-verbatim): cls/bbox from relu(pta0+pta1), fp32 -------------
__global__ __launch_bounds__(64) void heads2_kernel(
    const float* __restrict__ pta0, const float* __restrict__ pta1,
    const float* __restrict__ cls_w, const float* __restrict__ cls_b,
    const float* __restrict__ bbox_w, const float* __restrict__ bbox_b,
    float* __restrict__ out)
{
    const int n = blockIdx.x * 64 + threadIdx.x;
    const int b = n / HWP, p = n - b * HWP;
    const float* r0 = pta0 + (size_t)n * CC;
    const float* r1 = pta1 + (size_t)n * CC;
    float ac = 0.f, a0 = 0.f, a1 = 0.f, a2 = 0.f, a3 = 0.f;
    for (int c = 0; c < CC; c += 4) {
        const float4 u = *(const float4*)&r0[c];
        const float4 v = *(const float4*)&r1[c];
        float fv[4];
        fv[0] = fmaxf(u.x + v.x, 0.f);
        fv[1] = fmaxf(u.y + v.y, 0.f);
        fv[2] = fmaxf(u.z + v.z, 0.f);
        fv[3] = fmaxf(u.w + v.w, 0.f);
#pragma unroll
        for (int k = 0; k < 4; k++) {
            ac = fmaf(cls_w[c + k], fv[k], ac);
            a0 = fmaf(bbox_w[c + k], fv[k], a0);
            a1 = fmaf(bbox_w[CC + c + k], fv[k], a1);
            a2 = fmaf(bbox_w[2 * CC + c + k], fv[k], a2);
            a3 = fmaf(bbox_w[3 * CC + c + k], fv[k], a3);
        }
    }
    out[OUT_LOGITS + n] = ac + cls_b[0];
    out[OUT_BBOX + (b * 4 + 0) * HWP + p] = a0 + bbox_b[0];
    out[OUT_BBOX + (b * 4 + 1) * HWP + p] = a1 + bbox_b[1];
    out[OUT_BBOX + (b * 4 + 2) * HWP + p] = a2 + bbox_b[2];
    out[OUT_BBOX + (b * 4 + 3) * HWP + p] = a3 + bbox_b[3];
}

// ----------------------------------------------------------------------------
extern "C" void kernel_launch(void* const* d_in, const int* in_sizes, int n_in,
                              void* d_out, int out_size, void* d_ws, size_t ws_size,
                              hipStream_t stream)
{
    const float* feature  = (const float*)d_in[0];
    const float* conv_w   = (const float*)d_in[1];
    const float* conv_b   = (const float*)d_in[2];
    const float* loc_w    = (const float*)d_in[3];
    const float* loc_b    = (const float*)d_in[4];
    const float* shape_w  = (const float*)d_in[5];
    const float* shape_b  = (const float*)d_in[6];
    const float* offset_w = (const float*)d_in[7];
    const float* adapt_w  = (const float*)d_in[8];
    const float* cls_w    = (const float*)d_in[9];
    const float* cls_b    = (const float*)d_in[10];
    const float* bbox_w   = (const float*)d_in[11];
    const float* bbox_b   = (const float*)d_in[12];
    float* out = (float*)d_out;

    // workspace partition (~59 MB, R9-proven)
    float*          s0s1 = (float*)d_ws;                           // NTOT float2
    unsigned short* tcf  = (unsigned short*)(s0s1 + 2 * NTOT);     // NTOT*CC bf16
    unsigned short* fcf  = tcf + (size_t)NTOT * CC;                // NTOT*CC bf16
    unsigned short* W1   = fcf + (size_t)NTOT * CC;                // CC*K1 bf16
    unsigned short* W2   = W1 + (size_t)CC * K1;                   // CC*K1 bf16
    unsigned short* zp   = W2 + (size_t)CC * K1;                   // 1024 zeros
    float*          pta0 = (float*)(zp + 1024);                    // NTOT*CC fp32
    float*          pta1 = pta0 + (size_t)NTOT * CC;               // NTOT*CC fp32

    prep_kernel<<<(CC * K1 + 255) / 256, 256, 0, stream>>>(conv_w, adapt_w, W1, W2, zp);
    transpose_kernel<<<dim3(HWP / 64, 4, BB), 256, 0, stream>>>(feature, fcf);
    gemm1_kernel<<<dim3(NTOT / 64, 2), 256, 0, stream>>>(W1, fcf, conv_b, zp, tcf);
    heads1_kernel<<<dim3(NTOT / 64), 64, 0, stream>>>(
        tcf, loc_w, loc_b, shape_w, shape_b, out, s0s1);
    gemm2_fused_kernel<<<dim3(NTOT / 64, 2), 256, 0, stream>>>(
        W2, tcf, s0s1, offset_w, pta0, pta1);
    heads2_kernel<<<dim3(NTOT / 64), 64, 0, stream>>>(
        pta0, pta1, cls_w, cls_b, bbox_w, bbox_b, out);
}

// Round 12
// 293.832 us; speedup vs baseline: 1.4196x; 1.0111x over previous
//
#include <hip/hip_runtime.h>
#include <hip/hip_bf16.h>

// Problem constants
#define BB 2
#define CC 256
#define HH 96
#define WW 96
#define HWP (HH*WW)        // 9216
#define NTOT (BB*HWP)      // 18432 flattened (b,p)
#define K1 2304            // 256*9, GEMM K for both convs
#define NKT 36             // K1/64 k-steps
#define KHS 18             // k-steps per split-K half (gemm2)

// d_out layout: logits[2,1,96,96], bbox[2,4,96,96], shape[2,2,96,96], loc[2,1,96,96]
#define OUT_LOGITS 0
#define OUT_BBOX   (2*1*HWP)
#define OUT_SHAPE  (OUT_BBOX + 2*4*HWP)
#define OUT_LOC    (OUT_SHAPE + 2*2*HWP)

typedef __attribute__((ext_vector_type(8))) short short8v;   // 8 bf16 (4 VGPRs)
typedef __attribute__((ext_vector_type(4))) float f32x4;

typedef const __attribute__((address_space(1))) void* gptr_t;
typedef __attribute__((address_space(3))) void* lptr_t;
#define GLOAD16(g, l) __builtin_amdgcn_global_load_lds((gptr_t)(g), (lptr_t)(l), 16, 0, 0)

// XCD-aware swizzle: 288 n-blocks, 8 XCDs, round-robin dispatch assumption.
// Each XCD gets a contiguous 36-block (2304-pixel, 1.18 MB) slab -> L2-resident
// gather working set. Speed-only heuristic; any mapping is correct.
__device__ __forceinline__ int xcd_swizzle288(int bx) {
    return (bx & 7) * 36 + (bx >> 3);
}

__device__ __forceinline__ float bf2f(unsigned short u) {
    return __uint_as_float(((unsigned)u) << 16);
}
__device__ __forceinline__ unsigned short f2bf(float f) {
    unsigned u = __float_as_uint(f);
    u += 0x7FFFu + ((u >> 16) & 1u);           // round-to-nearest-even
    return (unsigned short)(u >> 16);
}

// ------- prep: weights -> bf16, BOTH in k = kk*256+ci order; zero page ------
__global__ __launch_bounds__(256) void prep_kernel(
    const float* __restrict__ conv_w, const float* __restrict__ adapt_w,
    unsigned short* __restrict__ W1, unsigned short* __restrict__ W2,
    unsigned short* __restrict__ zp)
{
    const int t = blockIdx.x * 256 + threadIdx.x;
    if (t < 1024) zp[t] = 0;                    // zero page (ws is re-poisoned!)
    if (t < CC * K1) {
        const int co = t / K1, r = t % K1;
        const int kk = r >> 8, ci = r & 255;    // k = kk*256+ci
        W1[t] = f2bf(conv_w[co * K1 + ci * 9 + kk]);
        W2[t] = f2bf(adapt_w[co * K1 + ci * 9 + kk]);
    }
}

// ------------- transpose feature [b][c][p] fp32 -> f_cf [b][p][c] bf16 ------
// grid (144, 4, 2): channel-group split across blockIdx.y (pure permutation).
__global__ __launch_bounds__(256) void transpose_kernel(
    const float* __restrict__ f, unsigned short* __restrict__ fcf)
{
    __shared__ unsigned short tile[64][66];     // +2 pad: conflict-free col reads
    const int p0 = blockIdx.x * 64;
    const int cc = blockIdx.y;
    const int b  = blockIdx.z;
    const int tx = threadIdx.x & 63, ty = threadIdx.x >> 6;
#pragma unroll
    for (int ii = 0; ii < 16; ii++) {
        const int cl = ii * 4 + ty;
        tile[cl][tx] = f2bf(f[((size_t)b * CC + cc * 64 + cl) * HWP + p0 + tx]);
    }
    __syncthreads();
#pragma unroll
    for (int ii = 0; ii < 16; ii++) {
        const int pl = ii * 4 + ty;
        fcf[((size_t)(b * HWP + p0 + pl)) * CC + cc * 64 + tx] = tile[tx][pl];
    }
}

// --------- GEMM1 (R11-verbatim + XCD swizzle): t = relu(W1 x im2col + bias) -
// 128M x 64N tile, BK=64, 4 waves (2x2), 16x16x32 MFMA, global_load_lds.
__global__ __launch_bounds__(256) void gemm1_kernel(
    const unsigned short* __restrict__ W1, const unsigned short* __restrict__ fcf,
    const float* __restrict__ bias, const unsigned short* __restrict__ zp,
    unsigned short* __restrict__ tcf)
{
    __shared__ short As[8192];                  // 128 rows x 64 k = 16 KB
    __shared__ short Bs[4096];                  // 64 rows x 64 k = 8 KB
    const int tid  = threadIdx.x;
    const int lane = tid & 63, w = tid >> 6;
    const int quad = lane >> 4, r15 = lane & 15;
    const int n0  = xcd_swizzle288(blockIdx.x) * 64;
    const int co0 = blockIdx.y * 128;
    const int wm = w >> 1, wn = w & 1;

    const int nb = n0 + lane;
    const int b  = nb / HWP;
    const int p  = nb - b * HWP;
    const int y = p / WW, x = p % WW;

    f32x4 acc[4][2];
#pragma unroll
    for (int i = 0; i < 4; i++)
#pragma unroll
        for (int j = 0; j < 2; j++) acc[i][j] = (f32x4){0.f, 0.f, 0.f, 0.f};

    for (int kt = 0; kt < NKT; kt++) {
        const int k0 = kt * 64;
#pragma unroll
        for (int i = 0; i < 4; i++) {           // A: 4 chunks/thread
            const int kc    = w * 2 + (i >> 1);
            const int row   = ((i & 1) << 6) + lane;
            const int sbase = w * 256 + i * 64;
            GLOAD16(W1 + (size_t)(co0 + row) * K1 + k0 + kc * 8, &As[sbase * 8]);
        }
#pragma unroll
        for (int i = 0; i < 2; i++) {           // B: 2 chunks/thread, implicit im2col
            const int kc    = w * 2 + i;
            const int sbase = w * 128 + i * 64;
            const int k   = k0 + kc * 8;
            const int kk  = k >> 8;
            const int ci0 = k & 255;
            const int yy = y + kk / 3 - 1, xx = x + kk % 3 - 1;
            const bool ok = (yy >= 0) && (yy < HH) && (xx >= 0) && (xx < WW);
            const unsigned short* gb = ok
                ? fcf + ((size_t)(b * HWP + yy * WW + xx)) * CC + ci0
                : zp;
            GLOAD16(gb, &Bs[sbase * 8]);
        }
        __syncthreads();
#pragma unroll
        for (int ks = 0; ks < 2; ks++) {
            short8v a[4], bf[2];
#pragma unroll
            for (int i = 0; i < 4; i++)
                a[i] = *(const short8v*)&As[(((ks * 4 + quad) * 128) + wm * 64 + i * 16 + r15) * 8];
#pragma unroll
            for (int j = 0; j < 2; j++)
                bf[j] = *(const short8v*)&Bs[(((ks * 4 + quad) * 64) + wn * 32 + j * 16 + r15) * 8];
#pragma unroll
            for (int i = 0; i < 4; i++)
#pragma unroll
                for (int j = 0; j < 2; j++)
                    acc[i][j] = __builtin_amdgcn_mfma_f32_16x16x32_bf16(a[i], bf[j], acc[i][j], 0, 0, 0);
        }
        __syncthreads();
    }
    // epilogue: bias + relu -> t_cf[n][c] bf16 (C/D map: col=lane&15, row=quad*4+reg)
#pragma unroll
    for (int i = 0; i < 4; i++) {
        const int m = co0 + wm * 64 + i * 16 + quad * 4;
        const float b0 = bias[m], b1 = bias[m + 1], b2 = bias[m + 2], b3 = bias[m + 3];
#pragma unroll
        for (int j = 0; j < 2; j++) {
            const int n = n0 + wn * 32 + j * 16 + r15;
            ushort4 st;
            st.x = f2bf(fmaxf(acc[i][j][0] + b0, 0.f));
            st.y = f2bf(fmaxf(acc[i][j][1] + b1, 0.f));
            st.z = f2bf(fmaxf(acc[i][j][2] + b2, 0.f));
            st.w = f2bf(fmaxf(acc[i][j][3] + b3, 0.f));
            *(ushort4*)(tcf + (size_t)n * CC + m) = st;
        }
    }
}

// ---- heads1 (R9-verbatim): loc/shape -> out; (s0,s1) per pixel -> ws -------
__global__ __launch_bounds__(64) void heads1_kernel(
    const unsigned short* __restrict__ tcf,
    const float* __restrict__ loc_w, const float* __restrict__ loc_b,
    const float* __restrict__ shape_w, const float* __restrict__ shape_b,
    float* __restrict__ out, float* __restrict__ s0s1)
{
    const int n = blockIdx.x * 64 + threadIdx.x;
    const int b = n / HWP, p = n - b * HWP;
    const unsigned short* row = tcf + (size_t)n * CC;
    float aloc = 0.f, s0 = 0.f, s1 = 0.f;
    for (int c = 0; c < CC; c += 8) {
        short8v v = *(const short8v*)&row[c];
#pragma unroll
        for (int k = 0; k < 8; k++) {
            const float fv = bf2f((unsigned short)v[k]);
            aloc = fmaf(loc_w[c + k], fv, aloc);
            s0   = fmaf(shape_w[c + k], fv, s0);
            s1   = fmaf(shape_w[CC + c + k], fv, s1);
        }
    }
    aloc += loc_b[0]; s0 += shape_b[0]; s1 += shape_b[1];
    out[OUT_LOC + n] = aloc;
    out[OUT_SHAPE + (b * 2 + 0) * HWP + p] = s0;
    out[OUT_SHAPE + (b * 2 + 1) * HWP + p] = s1;
    *(float2*)&s0s1[2 * n] = make_float2(s0, s1);
}

// ---- fused GEMM2 (R11-verbatim + XCD swizzle), split-K=2, M=256 x N=64 -----
// Block (n0, kh) does k-steps [18kh, 18kh+18). Each thread samples 2 pixels
// (pr0=tid>>3, pr1=pr0+32) x 8-ch chunk kc. fp32 partials, no relu.
__global__ __launch_bounds__(256) void gemm2_fused_kernel(
    const unsigned short* __restrict__ W2, const unsigned short* __restrict__ tcf,
    const float* __restrict__ s0s1, const float* __restrict__ offset_w,
    float* __restrict__ pta0, float* __restrict__ pta1)
{
    __shared__ short As[16384];                 // 8 kc-chunks x 256 rows x 16B = 32 KB
    __shared__ short Bs[64 * 9 * 8];            // padded layout, 9 KB
    const int tid  = threadIdx.x;
    const int lane = tid & 63, w = tid >> 6;
    const int quad = lane >> 4, r15 = lane & 15;
    const int n0  = xcd_swizzle288(blockIdx.x) * 64;
    const int kh  = blockIdx.y;                 // split-K half
    const int b   = n0 / HWP;                   // whole block in one batch
    const unsigned short* tb = tcf + (size_t)b * HWP * CC;

    // sampler mapping: thread -> pixels {pr0, pr1}, 8-ch chunk kc
    const int pr0 = tid >> 3, kc = tid & 7;
    int ys[2], xs[2];
    float2 s01s[2];
#pragma unroll
    for (int s = 0; s < 2; s++) {
        const int nb = n0 + pr0 + s * 32;
        const int p  = nb - b * HWP;
        ys[s] = p / WW; xs[s] = p % WW;
        s01s[s] = *(const float2*)&s0s1[2 * nb];
    }

    f32x4 acc[4][4];
#pragma unroll
    for (int i = 0; i < 4; i++)
#pragma unroll
        for (int j = 0; j < 4; j++) acc[i][j] = (f32x4){0.f, 0.f, 0.f, 0.f};

    for (int kt = kh * KHS; kt < kh * KHS + KHS; kt++) {
        const int k0 = kt * 64;
        const int kk = kt >> 2, g = kt & 3;
        // A: wave w stages kc-chunks {2w, 2w+1} x all 256 rows (slot = kc*256+row)
#pragma unroll
        for (int i = 0; i < 8; i++) {
            const int kca   = w * 2 + (i >> 2);
            const int rr    = (i & 3) * 64;          // + lane via DMA
            const int sbase = kca * 256 + rr;
            GLOAD16(W2 + (size_t)(rr + lane) * K1 + k0 + kca * 8, &As[sbase * 8]);
        }
        // B: bilinear sample of 8 channels x 2 pixels (R9-verbatim math)
#pragma unroll
        for (int s = 0; s < 2; s++) {
            const float2 s01 = s01s[s];
            const int y = ys[s], x = xs[s];
            const int o_dy = (g * 9 + kk) * 2, o_dx = o_dy + 1;
            const float dy = fmaf(offset_w[o_dy * 2], s01.x, offset_w[o_dy * 2 + 1] * s01.y);
            const float dx = fmaf(offset_w[o_dx * 2], s01.x, offset_w[o_dx * 2 + 1] * s01.y);
            const float py = (float)(y + kk / 3 - 1) + dy;
            const float px = (float)(x + kk % 3 - 1) + dx;
            const float y0f = floorf(py), x0f = floorf(px);
            const float wy = py - y0f, wx = px - x0f;
            const int y0 = (int)y0f, x0 = (int)x0f;
            const int y1 = y0 + 1, x1 = x0 + 1;
            const bool vy0 = (y0 >= 0) && (y0 < HH), vy1 = (y1 >= 0) && (y1 < HH);
            const bool vx0 = (x0 >= 0) && (x0 < WW), vx1 = (x1 >= 0) && (x1 < WW);
            const int y0c = min(max(y0, 0), HH - 1), y1c = min(max(y1, 0), HH - 1);
            const int x0c = min(max(x0, 0), WW - 1), x1c = min(max(x1, 0), WW - 1);
            const float w00 = (vy0 && vx0) ? (1.f - wy) * (1.f - wx) : 0.f;
            const float w01 = (vy0 && vx1) ? (1.f - wy) * wx         : 0.f;
            const float w10 = (vy1 && vx0) ? wy * (1.f - wx)         : 0.f;
            const float w11 = (vy1 && vx1) ? wy * wx                 : 0.f;
            const int ch = g * 64 + kc * 8;
            const short8v v00 = *(const short8v*)(tb + (size_t)(y0c * WW + x0c) * CC + ch);
            const short8v v01 = *(const short8v*)(tb + (size_t)(y0c * WW + x1c) * CC + ch);
            const short8v v10 = *(const short8v*)(tb + (size_t)(y1c * WW + x0c) * CC + ch);
            const short8v v11 = *(const short8v*)(tb + (size_t)(y1c * WW + x1c) * CC + ch);
            short8v r;
#pragma unroll
            for (int e = 0; e < 8; e++) {
                float val = w00 * bf2f((unsigned short)v00[e]);
                val = fmaf(w01, bf2f((unsigned short)v01[e]), val);
                val = fmaf(w10, bf2f((unsigned short)v10[e]), val);
                val = fmaf(w11, bf2f((unsigned short)v11[e]), val);
                r[e] = (short)f2bf(val);
            }
            *(short8v*)&Bs[((pr0 + s * 32) * 9 + kc) * 8] = r;
        }
        __syncthreads();
#pragma unroll
        for (int ks = 0; ks < 2; ks++) {
            short8v a[4], bf[4];
#pragma unroll
            for (int i = 0; i < 4; i++)
                a[i] = *(const short8v*)&As[(((ks * 4 + quad) * 256) + w * 64 + i * 16 + r15) * 8];
#pragma unroll
            for (int j = 0; j < 4; j++)
                bf[j] = *(const short8v*)&Bs[((j * 16 + r15) * 9 + ks * 4 + quad) * 8];
#pragma unroll
            for (int i = 0; i < 4; i++)
#pragma unroll
                for (int j = 0; j < 4; j++)
                    acc[i][j] = __builtin_amdgcn_mfma_f32_16x16x32_bf16(a[i], bf[j], acc[i][j], 0, 0, 0);
        }
        __syncthreads();
    }
    // epilogue: fp32 partial, no relu (C/D map: col=lane&15, row=quad*4+reg)
    float* pta = kh ? pta1 : pta0;
#pragma unroll
    for (int i = 0; i < 4; i++) {
        const int m = w * 64 + i * 16 + quad * 4;
#pragma unroll
        for (int j = 0; j < 4; j++) {
            const int n = n0 + j * 16 + r15;
            *(f32x4*)(pta + (size_t)n * CC + m) = acc[i][j];
        }
    }
}

// ---- heads2 (R9-verbatim): cls/bbox from relu(pta0+pta1), fp32 -------------
__global__ __launch_bounds__(64) void heads2_kernel(
    const float* __restrict__ pta0, const float* __restrict__ pta1,
    const float* __restrict__ cls_w, const float* __restrict__ cls_b,
    const float* __restrict__ bbox_w, const float* __restrict__ bbox_b,
    float* __restrict__ out)
{
    const int n = blockIdx.x * 64 + threadIdx.x;
    const int b = n / HWP, p = n - b * HWP;
    const float* r0 = pta0 + (size_t)n * CC;
    const float* r1 = pta1 + (size_t)n * CC;
    float ac = 0.f, a0 = 0.f, a1 = 0.f, a2 = 0.f, a3 = 0.f;
    for (int c = 0; c < CC; c += 4) {
        const float4 u = *(const float4*)&r0[c];
        const float4 v = *(const float4*)&r1[c];
        float fv[4];
        fv[0] = fmaxf(u.x + v.x, 0.f);
        fv[1] = fmaxf(u.y + v.y, 0.f);
        fv[2] = fmaxf(u.z + v.z, 0.f);
        fv[3] = fmaxf(u.w + v.w, 0.f);
#pragma unroll
        for (int k = 0; k < 4; k++) {
            ac = fmaf(cls_w[c + k], fv[k], ac);
            a0 = fmaf(bbox_w[c + k], fv[k], a0);
            a1 = fmaf(bbox_w[CC + c + k], fv[k], a1);
            a2 = fmaf(bbox_w[2 * CC + c + k], fv[k], a2);
            a3 = fmaf(bbox_w[3 * CC + c + k], fv[k], a3);
        }
    }
    out[OUT_LOGITS + n] = ac + cls_b[0];
    out[OUT_BBOX + (b * 4 + 0) * HWP + p] = a0 + bbox_b[0];
    out[OUT_BBOX + (b * 4 + 1) * HWP + p] = a1 + bbox_b[1];
    out[OUT_BBOX + (b * 4 + 2) * HWP + p] = a2 + bbox_b[2];
    out[OUT_BBOX + (b * 4 + 3) * HWP + p] = a3 + bbox_b[3];
}

// ----------------------------------------------------------------------------
extern "C" void kernel_launch(void* const* d_in, const int* in_sizes, int n_in,
                              void* d_out, int out_size, void* d_ws, size_t ws_size,
                              hipStream_t stream)
{
    const float* feature  = (const float*)d_in[0];
    const float* conv_w   = (const float*)d_in[1];
    const float* conv_b   = (const float*)d_in[2];
    const float* loc_w    = (const float*)d_in[3];
    const float* loc_b    = (const float*)d_in[4];
    const float* shape_w  = (const float*)d_in[5];
    const float* shape_b  = (const float*)d_in[6];
    const float* offset_w = (const float*)d_in[7];
    const float* adapt_w  = (const float*)d_in[8];
    const float* cls_w    = (const float*)d_in[9];
    const float* cls_b    = (const float*)d_in[10];
    const float* bbox_w   = (const float*)d_in[11];
    const float* bbox_b   = (const float*)d_in[12];
    float* out = (float*)d_out;

    // workspace partition (~59 MB, R9-proven)
    float*          s0s1 = (float*)d_ws;                           // NTOT float2
    unsigned short* tcf  = (unsigned short*)(s0s1 + 2 * NTOT);     // NTOT*CC bf16
    unsigned short* fcf  = tcf + (size_t)NTOT * CC;                // NTOT*CC bf16
    unsigned short* W1   = fcf + (size_t)NTOT * CC;                // CC*K1 bf16
    unsigned short* W2   = W1 + (size_t)CC * K1;                   // CC*K1 bf16
    unsigned short* zp   = W2 + (size_t)CC * K1;                   // 1024 zeros
    float*          pta0 = (float*)(zp + 1024);                    // NTOT*CC fp32
    float*          pta1 = pta0 + (size_t)NTOT * CC;               // NTOT*CC fp32

    prep_kernel<<<(CC * K1 + 255) / 256, 256, 0, stream>>>(conv_w, adapt_w, W1, W2, zp);
    transpose_kernel<<<dim3(HWP / 64, 4, BB), 256, 0, stream>>>(feature, fcf);
    gemm1_kernel<<<dim3(NTOT / 64, 2), 256, 0, stream>>>(W1, fcf, conv_b, zp, tcf);
    heads1_kernel<<<dim3(NTOT / 64), 64, 0, stream>>>(
        tcf, loc_w, loc_b, shape_w, shape_b, out, s0s1);
    gemm2_fused_kernel<<<dim3(NTOT / 64, 2), 256, 0, stream>>>(
        W2, tcf, s0s1, offset_w, pta0, pta1);
    heads2_kernel<<<dim3(NTOT / 64), 64, 0, stream>>>(
        pta0, pta1, cls_w, cls_b, bbox_w, bbox_b, out);
}

// Round 13
// 282.468 us; speedup vs baseline: 1.4767x; 1.0402x over previous
//
#include <hip/hip_runtime.h>
#include <hip/hip_bf16.h>

// Problem constants
#define BB 2
#define CC 256
#define HH 96
#define WW 96
#define HWP (HH*WW)        // 9216
#define NTOT (BB*HWP)      // 18432 flattened (b,p)
#define K1 2304            // 256*9, GEMM K for both convs
#define NKT 36             // K1/64 k-steps
#define KHS 18             // k-steps per split-K half (gemm2)

// d_out layout: logits[2,1,96,96], bbox[2,4,96,96], shape[2,2,96,96], loc[2,1,96,96]
#define OUT_LOGITS 0
#define OUT_BBOX   (2*1*HWP)
#define OUT_SHAPE  (OUT_BBOX + 2*4*HWP)
#define OUT_LOC    (OUT_SHAPE + 2*2*HWP)

typedef __attribute__((ext_vector_type(8))) short short8v;   // 8 bf16 (4 VGPRs)
typedef __attribute__((ext_vector_type(4))) float f32x4;

typedef const __attribute__((address_space(1))) void* gptr_t;
typedef __attribute__((address_space(3))) void* lptr_t;
#define GLOAD16(g, l) __builtin_amdgcn_global_load_lds((gptr_t)(g), (lptr_t)(l), 16, 0, 0)

// XCD-aware swizzle: 288 n-blocks, 8 XCDs. Each XCD gets a contiguous
// 36-block (2304-pixel, 1.18 MB) slab -> L2-resident gather working set.
// [R12 measured: FETCH 56 -> 11.7 MB. Keeper.]
__device__ __forceinline__ int xcd_swizzle288(int bx) {
    return (bx & 7) * 36 + (bx >> 3);
}

__device__ __forceinline__ float bf2f(unsigned short u) {
    return __uint_as_float(((unsigned)u) << 16);
}
__device__ __forceinline__ unsigned short f2bf(float f) {
    unsigned u = __float_as_uint(f);
    u += 0x7FFFu + ((u >> 16) & 1u);           // round-to-nearest-even
    return (unsigned short)(u >> 16);
}

// ------- prep: weights -> bf16, BOTH in k = kk*256+ci order; zero page ------
__global__ __launch_bounds__(256) void prep_kernel(
    const float* __restrict__ conv_w, const float* __restrict__ adapt_w,
    unsigned short* __restrict__ W1, unsigned short* __restrict__ W2,
    unsigned short* __restrict__ zp)
{
    const int t = blockIdx.x * 256 + threadIdx.x;
    if (t < 1024) zp[t] = 0;                    // zero page (ws is re-poisoned!)
    if (t < CC * K1) {
        const int co = t / K1, r = t % K1;
        const int kk = r >> 8, ci = r & 255;    // k = kk*256+ci
        W1[t] = f2bf(conv_w[co * K1 + ci * 9 + kk]);
        W2[t] = f2bf(adapt_w[co * K1 + ci * 9 + kk]);
    }
}

// ------------- transpose feature [b][c][p] fp32 -> f_cf [b][p][c] bf16 ------
// grid (144, 4, 2): channel-group split across blockIdx.y (pure permutation).
__global__ __launch_bounds__(256) void transpose_kernel(
    const float* __restrict__ f, unsigned short* __restrict__ fcf)
{
    __shared__ unsigned short tile[64][66];     // +2 pad: conflict-free col reads
    const int p0 = blockIdx.x * 64;
    const int cc = blockIdx.y;
    const int b  = blockIdx.z;
    const int tx = threadIdx.x & 63, ty = threadIdx.x >> 6;
#pragma unroll
    for (int ii = 0; ii < 16; ii++) {
        const int cl = ii * 4 + ty;
        tile[cl][tx] = f2bf(f[((size_t)b * CC + cc * 64 + cl) * HWP + p0 + tx]);
    }
    __syncthreads();
#pragma unroll
    for (int ii = 0; ii < 16; ii++) {
        const int pl = ii * 4 + ty;
        fcf[((size_t)(b * HWP + p0 + pl)) * CC + cc * 64 + tx] = tile[tx][pl];
    }
}

// --------- GEMM1 (R12-verbatim): t = relu(W1 x im2col + bias) ---------------
// 128M x 64N tile, BK=64, 4 waves (2x2), 16x16x32 MFMA, global_load_lds.
__global__ __launch_bounds__(256) void gemm1_kernel(
    const unsigned short* __restrict__ W1, const unsigned short* __restrict__ fcf,
    const float* __restrict__ bias, const unsigned short* __restrict__ zp,
    unsigned short* __restrict__ tcf)
{
    __shared__ short As[8192];                  // 128 rows x 64 k = 16 KB
    __shared__ short Bs[4096];                  // 64 rows x 64 k = 8 KB
    const int tid  = threadIdx.x;
    const int lane = tid & 63, w = tid >> 6;
    const int quad = lane >> 4, r15 = lane & 15;
    const int n0  = xcd_swizzle288(blockIdx.x) * 64;
    const int co0 = blockIdx.y * 128;
    const int wm = w >> 1, wn = w & 1;

    const int nb = n0 + lane;
    const int b  = nb / HWP;
    const int p  = nb - b * HWP;
    const int y = p / WW, x = p % WW;

    f32x4 acc[4][2];
#pragma unroll
    for (int i = 0; i < 4; i++)
#pragma unroll
        for (int j = 0; j < 2; j++) acc[i][j] = (f32x4){0.f, 0.f, 0.f, 0.f};

    for (int kt = 0; kt < NKT; kt++) {
        const int k0 = kt * 64;
#pragma unroll
        for (int i = 0; i < 4; i++) {           // A: 4 chunks/thread
            const int kc    = w * 2 + (i >> 1);
            const int row   = ((i & 1) << 6) + lane;
            const int sbase = w * 256 + i * 64;
            GLOAD16(W1 + (size_t)(co0 + row) * K1 + k0 + kc * 8, &As[sbase * 8]);
        }
#pragma unroll
        for (int i = 0; i < 2; i++) {           // B: 2 chunks/thread, implicit im2col
            const int kc    = w * 2 + i;
            const int sbase = w * 128 + i * 64;
            const int k   = k0 + kc * 8;
            const int kk  = k >> 8;
            const int ci0 = k & 255;
            const int yy = y + kk / 3 - 1, xx = x + kk % 3 - 1;
            const bool ok = (yy >= 0) && (yy < HH) && (xx >= 0) && (xx < WW);
            const unsigned short* gb = ok
                ? fcf + ((size_t)(b * HWP + yy * WW + xx)) * CC + ci0
                : zp;
            GLOAD16(gb, &Bs[sbase * 8]);
        }
        __syncthreads();
#pragma unroll
        for (int ks = 0; ks < 2; ks++) {
            short8v a[4], bf[2];
#pragma unroll
            for (int i = 0; i < 4; i++)
                a[i] = *(const short8v*)&As[(((ks * 4 + quad) * 128) + wm * 64 + i * 16 + r15) * 8];
#pragma unroll
            for (int j = 0; j < 2; j++)
                bf[j] = *(const short8v*)&Bs[(((ks * 4 + quad) * 64) + wn * 32 + j * 16 + r15) * 8];
#pragma unroll
            for (int i = 0; i < 4; i++)
#pragma unroll
                for (int j = 0; j < 2; j++)
                    acc[i][j] = __builtin_amdgcn_mfma_f32_16x16x32_bf16(a[i], bf[j], acc[i][j], 0, 0, 0);
        }
        __syncthreads();
    }
    // epilogue: bias + relu -> t_cf[n][c] bf16 (C/D map: col=lane&15, row=quad*4+reg)
#pragma unroll
    for (int i = 0; i < 4; i++) {
        const int m = co0 + wm * 64 + i * 16 + quad * 4;
        const float b0 = bias[m], b1 = bias[m + 1], b2 = bias[m + 2], b3 = bias[m + 3];
#pragma unroll
        for (int j = 0; j < 2; j++) {
            const int n = n0 + wn * 32 + j * 16 + r15;
            ushort4 st;
            st.x = f2bf(fmaxf(acc[i][j][0] + b0, 0.f));
            st.y = f2bf(fmaxf(acc[i][j][1] + b1, 0.f));
            st.z = f2bf(fmaxf(acc[i][j][2] + b2, 0.f));
            st.w = f2bf(fmaxf(acc[i][j][3] + b3, 0.f));
            *(ushort4*)(tcf + (size_t)n * CC + m) = st;
        }
    }
}

// ---- heads1 (R9-verbatim): loc/shape -> out; (s0,s1) per pixel -> ws -------
__global__ __launch_bounds__(64) void heads1_kernel(
    const unsigned short* __restrict__ tcf,
    const float* __restrict__ loc_w, const float* __restrict__ loc_b,
    const float* __restrict__ shape_w, const float* __restrict__ shape_b,
    float* __restrict__ out, float* __restrict__ s0s1)
{
    const int n = blockIdx.x * 64 + threadIdx.x;
    const int b = n / HWP, p = n - b * HWP;
    const unsigned short* row = tcf + (size_t)n * CC;
    float aloc = 0.f, s0 = 0.f, s1 = 0.f;
    for (int c = 0; c < CC; c += 8) {
        short8v v = *(const short8v*)&row[c];
#pragma unroll
        for (int k = 0; k < 8; k++) {
            const float fv = bf2f((unsigned short)v[k]);
            aloc = fmaf(loc_w[c + k], fv, aloc);
            s0   = fmaf(shape_w[c + k], fv, s0);
            s1   = fmaf(shape_w[CC + c + k], fv, s1);
        }
    }
    aloc += loc_b[0]; s0 += shape_b[0]; s1 += shape_b[1];
    out[OUT_LOC + n] = aloc;
    out[OUT_SHAPE + (b * 2 + 0) * HWP + p] = s0;
    out[OUT_SHAPE + (b * 2 + 1) * HWP + p] = s1;
    *(float2*)&s0s1[2 * n] = make_float2(s0, s1);
}

// ---- fused GEMM2, split-K=2, M=256 x N=64, 512 threads / 8 waves -----------
// R12 lesson: FETCH fix didn't move dur -> latency-bound on barrier-serialized
// chain with ~4 waves/CU. Same LDS (41 KB), same tile, DOUBLE the waves:
// wave w = (co-quarter w&3, n-half w>>2); each thread samples ONE pixel
// (pr=tid>>3, kc=tid&7) with bit-identical per-pixel math; A: 4 GLOAD16/thread.
__global__ __launch_bounds__(512, 6) void gemm2_fused_kernel(
    const unsigned short* __restrict__ W2, const unsigned short* __restrict__ tcf,
    const float* __restrict__ s0s1, const float* __restrict__ offset_w,
    float* __restrict__ pta0, float* __restrict__ pta1)
{
    __shared__ short As[16384];                 // 8 kc-chunks x 256 rows x 16B = 32 KB
    __shared__ short Bs[64 * 9 * 8];            // padded layout, 9 KB
    const int tid  = threadIdx.x;
    const int lane = tid & 63, w = tid >> 6;    // w in [0,8)
    const int quad = lane >> 4, r15 = lane & 15;
    const int n0  = xcd_swizzle288(blockIdx.x) * 64;
    const int kh  = blockIdx.y;                 // split-K half
    const int b   = n0 / HWP;                   // whole block in one batch
    const unsigned short* tb = tcf + (size_t)b * HWP * CC;
    const int wm = w & 3, wn = w >> 2;          // co-quarter, n-half

    // sampler mapping: thread -> pixel pr, 8-ch chunk kc (one pixel/thread)
    const int pr = tid >> 3, kc = tid & 7;
    const int nb = n0 + pr;
    const int p  = nb - b * HWP;
    const int y = p / WW, x = p % WW;
    const float2 s01 = *(const float2*)&s0s1[2 * nb];

    f32x4 acc[4][2];
#pragma unroll
    for (int i = 0; i < 4; i++)
#pragma unroll
        for (int j = 0; j < 2; j++) acc[i][j] = (f32x4){0.f, 0.f, 0.f, 0.f};

    for (int kt = kh * KHS; kt < kh * KHS + KHS; kt++) {
        const int k0 = kt * 64;
        const int kk = kt >> 2, g = kt & 3;
        // A: wave w stages kc-chunk w x all 256 rows (slot = kc*256+row)
#pragma unroll
        for (int i = 0; i < 4; i++) {
            const int rr    = i * 64;                // + lane via DMA
            const int sbase = w * 256 + rr;
            GLOAD16(W2 + (size_t)(rr + lane) * K1 + k0 + w * 8, &As[sbase * 8]);
        }
        // B: bilinear sample of 8 channels (R9-verbatim per-pixel math)
        {
            const int o_dy = (g * 9 + kk) * 2, o_dx = o_dy + 1;
            const float dy = fmaf(offset_w[o_dy * 2], s01.x, offset_w[o_dy * 2 + 1] * s01.y);
            const float dx = fmaf(offset_w[o_dx * 2], s01.x, offset_w[o_dx * 2 + 1] * s01.y);
            const float py = (float)(y + kk / 3 - 1) + dy;
            const float px = (float)(x + kk % 3 - 1) + dx;
            const float y0f = floorf(py), x0f = floorf(px);
            const float wy = py - y0f, wx = px - x0f;
            const int y0 = (int)y0f, x0 = (int)x0f;
            const int y1 = y0 + 1, x1 = x0 + 1;
            const bool vy0 = (y0 >= 0) && (y0 < HH), vy1 = (y1 >= 0) && (y1 < HH);
            const bool vx0 = (x0 >= 0) && (x0 < WW), vx1 = (x1 >= 0) && (x1 < WW);
            const int y0c = min(max(y0, 0), HH - 1), y1c = min(max(y1, 0), HH - 1);
            const int x0c = min(max(x0, 0), WW - 1), x1c = min(max(x1, 0), WW - 1);
            const float w00 = (vy0 && vx0) ? (1.f - wy) * (1.f - wx) : 0.f;
            const float w01 = (vy0 && vx1) ? (1.f - wy) * wx         : 0.f;
            const float w10 = (vy1 && vx0) ? wy * (1.f - wx)         : 0.f;
            const float w11 = (vy1 && vx1) ? wy * wx                 : 0.f;
            const int ch = g * 64 + kc * 8;
            const short8v v00 = *(const short8v*)(tb + (size_t)(y0c * WW + x0c) * CC + ch);
            const short8v v01 = *(const short8v*)(tb + (size_t)(y0c * WW + x1c) * CC + ch);
            const short8v v10 = *(const short8v*)(tb + (size_t)(y1c * WW + x0c) * CC + ch);
            const short8v v11 = *(const short8v*)(tb + (size_t)(y1c * WW + x1c) * CC + ch);
            short8v r;
#pragma unroll
            for (int e = 0; e < 8; e++) {
                float val = w00 * bf2f((unsigned short)v00[e]);
                val = fmaf(w01, bf2f((unsigned short)v01[e]), val);
                val = fmaf(w10, bf2f((unsigned short)v10[e]), val);
                val = fmaf(w11, bf2f((unsigned short)v11[e]), val);
                r[e] = (short)f2bf(val);
            }
            *(short8v*)&Bs[(pr * 9 + kc) * 8] = r;
        }
        __syncthreads();
#pragma unroll
        for (int ks = 0; ks < 2; ks++) {
            short8v a[4], bf[2];
#pragma unroll
            for (int i = 0; i < 4; i++)
                a[i] = *(const short8v*)&As[(((ks * 4 + quad) * 256) + wm * 64 + i * 16 + r15) * 8];
#pragma unroll
            for (int j = 0; j < 2; j++)
                bf[j] = *(const short8v*)&Bs[((wn * 32 + j * 16 + r15) * 9 + ks * 4 + quad) * 8];
#pragma unroll
            for (int i = 0; i < 4; i++)
#pragma unroll
                for (int j = 0; j < 2; j++)
                    acc[i][j] = __builtin_amdgcn_mfma_f32_16x16x32_bf16(a[i], bf[j], acc[i][j], 0, 0, 0);
        }
        __syncthreads();
    }
    // epilogue: fp32 partial, no relu (C/D map: col=lane&15, row=quad*4+reg)
    float* pta = kh ? pta1 : pta0;
#pragma unroll
    for (int i = 0; i < 4; i++) {
        const int m = wm * 64 + i * 16 + quad * 4;
#pragma unroll
        for (int j = 0; j < 2; j++) {
            const int n = n0 + wn * 32 + j * 16 + r15;
            *(f32x4*)(pta + (size_t)n * CC + m) = acc[i][j];
        }
    }
}

// ---- heads2 (R9-verbatim): cls/bbox from relu(pta0+pta1), fp32 -------------
__global__ __launch_bounds__(64) void heads2_kernel(
    const float* __restrict__ pta0, const float* __restrict__ pta1,
    const float* __restrict__ cls_w, const float* __restrict__ cls_b,
    const float* __restrict__ bbox_w, const float* __restrict__ bbox_b,
    float* __restrict__ out)
{
    const int n = blockIdx.x * 64 + threadIdx.x;
    const int b = n / HWP, p = n - b * HWP;
    const float* r0 = pta0 + (size_t)n * CC;
    const float* r1 = pta1 + (size_t)n * CC;
    float ac = 0.f, a0 = 0.f, a1 = 0.f, a2 = 0.f, a3 = 0.f;
    for (int c = 0; c < CC; c += 4) {
        const float4 u = *(const float4*)&r0[c];
        const float4 v = *(const float4*)&r1[c];
        float fv[4];
        fv[0] = fmaxf(u.x + v.x, 0.f);
        fv[1] = fmaxf(u.y + v.y, 0.f);
        fv[2] = fmaxf(u.z + v.z, 0.f);
        fv[3] = fmaxf(u.w + v.w, 0.f);
#pragma unroll
        for (int k = 0; k < 4; k++) {
            ac = fmaf(cls_w[c + k], fv[k], ac);
            a0 = fmaf(bbox_w[c + k], fv[k], a0);
            a1 = fmaf(bbox_w[CC + c + k], fv[k], a1);
            a2 = fmaf(bbox_w[2 * CC + c + k], fv[k], a2);
            a3 = fmaf(bbox_w[3 * CC + c + k], fv[k], a3);
        }
    }
    out[OUT_LOGITS + n] = ac + cls_b[0];
    out[OUT_BBOX + (b * 4 + 0) * HWP + p] = a0 + bbox_b[0];
    out[OUT_BBOX + (b * 4 + 1) * HWP + p] = a1 + bbox_b[1];
    out[OUT_BBOX + (b * 4 + 2) * HWP + p] = a2 + bbox_b[2];
    out[OUT_BBOX + (b * 4 + 3) * HWP + p] = a3 + bbox_b[3];
}

// ----------------------------------------------------------------------------
extern "C" void kernel_launch(void* const* d_in, const int* in_sizes, int n_in,
                              void* d_out, int out_size, void* d_ws, size_t ws_size,
                              hipStream_t stream)
{
    const float* feature  = (const float*)d_in[0];
    const float* conv_w   = (const float*)d_in[1];
    const float* conv_b   = (const float*)d_in[2];
    const float* loc_w    = (const float*)d_in[3];
    const float* loc_b    = (const float*)d_in[4];
    const float* shape_w  = (const float*)d_in[5];
    const float* shape_b  = (const float*)d_in[6];
    const float* offset_w = (const float*)d_in[7];
    const float* adapt_w  = (const float*)d_in[8];
    const float* cls_w    = (const float*)d_in[9];
    const float* cls_b    = (const float*)d_in[10];
    const float* bbox_w   = (const float*)d_in[11];
    const float* bbox_b   = (const float*)d_in[12];
    float* out = (float*)d_out;

    // workspace partition (~59 MB, R9-proven)
    float*          s0s1 = (float*)d_ws;                           // NTOT float2
    unsigned short* tcf  = (unsigned short*)(s0s1 + 2 * NTOT);     // NTOT*CC bf16
    unsigned short* fcf  = tcf + (size_t)NTOT * CC;                // NTOT*CC bf16
    unsigned short* W1   = fcf + (size_t)NTOT * CC;                // CC*K1 bf16
    unsigned short* W2   = W1 + (size_t)CC * K1;                   // CC*K1 bf16
    unsigned short* zp   = W2 + (size_t)CC * K1;                   // 1024 zeros
    float*          pta0 = (float*)(zp + 1024);                    // NTOT*CC fp32
    float*          pta1 = pta0 + (size_t)NTOT * CC;               // NTOT*CC fp32

    prep_kernel<<<(CC * K1 + 255) / 256, 256, 0, stream>>>(conv_w, adapt_w, W1, W2, zp);
    transpose_kernel<<<dim3(HWP / 64, 4, BB), 256, 0, stream>>>(feature, fcf);
    gemm1_kernel<<<dim3(NTOT / 64, 2), 256, 0, stream>>>(W1, fcf, conv_b, zp, tcf);
    heads1_kernel<<<dim3(NTOT / 64), 64, 0, stream>>>(
        tcf, loc_w, loc_b, shape_w, shape_b, out, s0s1);
    gemm2_fused_kernel<<<dim3(NTOT / 64, 2), 512, 0, stream>>>(
        W2, tcf, s0s1, offset_w, pta0, pta1);
    heads2_kernel<<<dim3(NTOT / 64), 64, 0, stream>>>(
        pta0, pta1, cls_w, cls_b, bbox_w, bbox_b, out);
}

// Round 14
// 270.597 us; speedup vs baseline: 1.5415x; 1.0439x over previous
//
#include <hip/hip_runtime.h>
#include <hip/hip_bf16.h>

// Problem constants
#define BB 2
#define CC 256
#define HH 96
#define WW 96
#define HWP (HH*WW)        // 9216
#define NTOT (BB*HWP)      // 18432 flattened (b,p)
#define K1 2304            // 256*9, GEMM K for both convs
#define NKT 36             // K1/64 k-steps
#define KHS 18             // k-steps per split-K half (gemm2)

// d_out layout: logits[2,1,96,96], bbox[2,4,96,96], shape[2,2,96,96], loc[2,1,96,96]
#define OUT_LOGITS 0
#define OUT_BBOX   (2*1*HWP)
#define OUT_SHAPE  (OUT_BBOX + 2*4*HWP)
#define OUT_LOC    (OUT_SHAPE + 2*2*HWP)

typedef __attribute__((ext_vector_type(8))) short short8v;   // 8 bf16 (4 VGPRs)
typedef __attribute__((ext_vector_type(4))) float f32x4;

typedef const __attribute__((address_space(1))) void* gptr_t;
typedef __attribute__((address_space(3))) void* lptr_t;
#define GLOAD16(g, l) __builtin_amdgcn_global_load_lds((gptr_t)(g), (lptr_t)(l), 16, 0, 0)

// XCD-aware swizzle: 288 n-blocks, 8 XCDs. Each XCD gets a contiguous
// 36-block (2304-pixel, 1.18 MB) slab -> L2-resident gather working set.
// [R12 measured: FETCH 56 -> 11.7 MB. Keeper.]
__device__ __forceinline__ int xcd_swizzle288(int bx) {
    return (bx & 7) * 36 + (bx >> 3);
}

__device__ __forceinline__ float bf2f(unsigned short u) {
    return __uint_as_float(((unsigned)u) << 16);
}
__device__ __forceinline__ unsigned short f2bf(float f) {
    unsigned u = __float_as_uint(f);
    u += 0x7FFFu + ((u >> 16) & 1u);           // round-to-nearest-even
    return (unsigned short)(u >> 16);
}

// ------- prep: weights -> bf16, BOTH in k = kk*256+ci order; zero page ------
__global__ __launch_bounds__(256) void prep_kernel(
    const float* __restrict__ conv_w, const float* __restrict__ adapt_w,
    unsigned short* __restrict__ W1, unsigned short* __restrict__ W2,
    unsigned short* __restrict__ zp)
{
    const int t = blockIdx.x * 256 + threadIdx.x;
    if (t < 1024) zp[t] = 0;                    // zero page (ws is re-poisoned!)
    if (t < CC * K1) {
        const int co = t / K1, r = t % K1;
        const int kk = r >> 8, ci = r & 255;    // k = kk*256+ci
        W1[t] = f2bf(conv_w[co * K1 + ci * 9 + kk]);
        W2[t] = f2bf(adapt_w[co * K1 + ci * 9 + kk]);
    }
}

// ------------- transpose feature [b][c][p] fp32 -> f_cf [b][p][c] bf16 ------
// grid (144, 4, 2): channel-group split across blockIdx.y (pure permutation).
__global__ __launch_bounds__(256) void transpose_kernel(
    const float* __restrict__ f, unsigned short* __restrict__ fcf)
{
    __shared__ unsigned short tile[64][66];     // +2 pad: conflict-free col reads
    const int p0 = blockIdx.x * 64;
    const int cc = blockIdx.y;
    const int b  = blockIdx.z;
    const int tx = threadIdx.x & 63, ty = threadIdx.x >> 6;
#pragma unroll
    for (int ii = 0; ii < 16; ii++) {
        const int cl = ii * 4 + ty;
        tile[cl][tx] = f2bf(f[((size_t)b * CC + cc * 64 + cl) * HWP + p0 + tx]);
    }
    __syncthreads();
#pragma unroll
    for (int ii = 0; ii < 16; ii++) {
        const int pl = ii * 4 + ty;
        fcf[((size_t)(b * HWP + p0 + pl)) * CC + cc * 64 + tx] = tile[tx][pl];
    }
}

// --------- GEMM1: t = relu(W1 x im2col + bias), 512 threads / 8 waves -------
// Same M=128 x N=64 tile, BK=64, same LDS layouts as R13; wave w stages
// kc-chunk w (A: 2 GLOAD16, B: 1 GLOAD16/thread); wave = (co-quarter w&3,
// n-half w>>2). R13 lesson applied to gemm1: double waves at constant LDS.
__global__ __launch_bounds__(512, 6) void gemm1_kernel(
    const unsigned short* __restrict__ W1, const unsigned short* __restrict__ fcf,
    const float* __restrict__ bias, const unsigned short* __restrict__ zp,
    unsigned short* __restrict__ tcf)
{
    __shared__ short As[8192];                  // 128 rows x 64 k = 16 KB
    __shared__ short Bs[4096];                  // 64 rows x 64 k = 8 KB
    const int tid  = threadIdx.x;
    const int lane = tid & 63, w = tid >> 6;    // w in [0,8)
    const int quad = lane >> 4, r15 = lane & 15;
    const int n0  = xcd_swizzle288(blockIdx.x) * 64;
    const int co0 = blockIdx.y * 128;
    const int wm = w & 3, wn = w >> 2;          // co-quarter (32 rows), n-half

    const int nb = n0 + lane;
    const int b  = nb / HWP;
    const int p  = nb - b * HWP;
    const int y = p / WW, x = p % WW;
    const unsigned short* fb = fcf + (size_t)b * HWP * CC;

    f32x4 acc[2][2];
#pragma unroll
    for (int i = 0; i < 2; i++)
#pragma unroll
        for (int j = 0; j < 2; j++) acc[i][j] = (f32x4){0.f, 0.f, 0.f, 0.f};

    for (int kt = 0; kt < NKT; kt++) {
        const int k0 = kt * 64;
        // A: wave w stages kc-chunk w, rows {lane, lane+64} (slot = kc*128+row)
#pragma unroll
        for (int i = 0; i < 2; i++) {
            const int rr = i * 64;              // + lane via DMA
            GLOAD16(W1 + (size_t)(co0 + rr + lane) * K1 + k0 + w * 8,
                    &As[(w * 128 + rr) * 8]);
        }
        // B: wave w stages kc-chunk w, row = lane (implicit im2col)
        {
            const int k   = k0 + w * 8;
            const int kk  = k >> 8;
            const int ci0 = k & 255;
            const int yy = y + kk / 3 - 1, xx = x + kk % 3 - 1;
            const bool ok = (yy >= 0) && (yy < HH) && (xx >= 0) && (xx < WW);
            const unsigned short* gb = ok
                ? fb + (size_t)(yy * WW + xx) * CC + ci0
                : zp;
            GLOAD16(gb, &Bs[(w * 64) * 8]);
        }
        __syncthreads();
#pragma unroll
        for (int ks = 0; ks < 2; ks++) {
            short8v a[2], bf[2];
#pragma unroll
            for (int i = 0; i < 2; i++)
                a[i] = *(const short8v*)&As[(((ks * 4 + quad) * 128) + wm * 32 + i * 16 + r15) * 8];
#pragma unroll
            for (int j = 0; j < 2; j++)
                bf[j] = *(const short8v*)&Bs[(((ks * 4 + quad) * 64) + wn * 32 + j * 16 + r15) * 8];
#pragma unroll
            for (int i = 0; i < 2; i++)
#pragma unroll
                for (int j = 0; j < 2; j++)
                    acc[i][j] = __builtin_amdgcn_mfma_f32_16x16x32_bf16(a[i], bf[j], acc[i][j], 0, 0, 0);
        }
        __syncthreads();
    }
    // epilogue: bias + relu -> t_cf[n][c] bf16 (C/D map: col=lane&15, row=quad*4+reg)
#pragma unroll
    for (int i = 0; i < 2; i++) {
        const int m = co0 + wm * 32 + i * 16 + quad * 4;
        const float b0 = bias[m], b1 = bias[m + 1], b2 = bias[m + 2], b3 = bias[m + 3];
#pragma unroll
        for (int j = 0; j < 2; j++) {
            const int n = n0 + wn * 32 + j * 16 + r15;
            ushort4 st;
            st.x = f2bf(fmaxf(acc[i][j][0] + b0, 0.f));
            st.y = f2bf(fmaxf(acc[i][j][1] + b1, 0.f));
            st.z = f2bf(fmaxf(acc[i][j][2] + b2, 0.f));
            st.w = f2bf(fmaxf(acc[i][j][3] + b3, 0.f));
            *(ushort4*)(tcf + (size_t)n * CC + m) = st;
        }
    }
}

// ---- heads1: wave-per-pixel, lane = 4-channel chunk (coalesced row read) ---
// Row read: 64 lanes x ushort4 (8B) = one 512B coalesced burst per pixel.
// Butterfly shfl reduce (order change vs sequential: ~1e-6, margin is 4x).
__global__ __launch_bounds__(256) void heads1_kernel(
    const unsigned short* __restrict__ tcf,
    const float* __restrict__ loc_w, const float* __restrict__ loc_b,
    const float* __restrict__ shape_w, const float* __restrict__ shape_b,
    float* __restrict__ out, float* __restrict__ s0s1)
{
    const int lane = threadIdx.x & 63, wv = threadIdx.x >> 6;
    const int n = blockIdx.x * 4 + wv;
    const int b = n / HWP, p = n - b * HWP;
    const int c = lane * 4;
    const ushort4 v = *(const ushort4*)(tcf + (size_t)n * CC + c);
    const float f0 = bf2f(v.x), f1 = bf2f(v.y), f2 = bf2f(v.z), f3 = bf2f(v.w);
    float aloc, s0, s1;
    aloc = loc_w[c] * f0;           aloc = fmaf(loc_w[c+1], f1, aloc);
    aloc = fmaf(loc_w[c+2], f2, aloc); aloc = fmaf(loc_w[c+3], f3, aloc);
    s0 = shape_w[c] * f0;           s0 = fmaf(shape_w[c+1], f1, s0);
    s0 = fmaf(shape_w[c+2], f2, s0);   s0 = fmaf(shape_w[c+3], f3, s0);
    s1 = shape_w[CC+c] * f0;        s1 = fmaf(shape_w[CC+c+1], f1, s1);
    s1 = fmaf(shape_w[CC+c+2], f2, s1); s1 = fmaf(shape_w[CC+c+3], f3, s1);
#pragma unroll
    for (int off = 32; off; off >>= 1) {
        aloc += __shfl_xor(aloc, off);
        s0   += __shfl_xor(s0, off);
        s1   += __shfl_xor(s1, off);
    }
    if (lane == 0) {
        const float l = aloc + loc_b[0], a = s0 + shape_b[0], cc2 = s1 + shape_b[1];
        out[OUT_LOC + n] = l;
        out[OUT_SHAPE + (b * 2 + 0) * HWP + p] = a;
        out[OUT_SHAPE + (b * 2 + 1) * HWP + p] = cc2;
        *(float2*)&s0s1[2 * n] = make_float2(a, cc2);
    }
}

// ---- fused GEMM2 (R13-verbatim loop), split-K=2, M=256 x N=64, 512 thr -----
// Epilogue changed: pta stored c-major pta[c*NTOT + n] -> coalesced heads2.
__global__ __launch_bounds__(512, 6) void gemm2_fused_kernel(
    const unsigned short* __restrict__ W2, const unsigned short* __restrict__ tcf,
    const float* __restrict__ s0s1, const float* __restrict__ offset_w,
    float* __restrict__ pta0, float* __restrict__ pta1)
{
    __shared__ short As[16384];                 // 8 kc-chunks x 256 rows x 16B = 32 KB
    __shared__ short Bs[64 * 9 * 8];            // padded layout, 9 KB
    const int tid  = threadIdx.x;
    const int lane = tid & 63, w = tid >> 6;    // w in [0,8)
    const int quad = lane >> 4, r15 = lane & 15;
    const int n0  = xcd_swizzle288(blockIdx.x) * 64;
    const int kh  = blockIdx.y;                 // split-K half
    const int b   = n0 / HWP;                   // whole block in one batch
    const unsigned short* tb = tcf + (size_t)b * HWP * CC;
    const int wm = w & 3, wn = w >> 2;          // co-quarter, n-half

    // sampler mapping: thread -> pixel pr, 8-ch chunk kc (one pixel/thread)
    const int pr = tid >> 3, kc = tid & 7;
    const int nb = n0 + pr;
    const int p  = nb - b * HWP;
    const int y = p / WW, x = p % WW;
    const float2 s01 = *(const float2*)&s0s1[2 * nb];

    f32x4 acc[4][2];
#pragma unroll
    for (int i = 0; i < 4; i++)
#pragma unroll
        for (int j = 0; j < 2; j++) acc[i][j] = (f32x4){0.f, 0.f, 0.f, 0.f};

    for (int kt = kh * KHS; kt < kh * KHS + KHS; kt++) {
        const int k0 = kt * 64;
        const int kk = kt >> 2, g = kt & 3;
        // A: wave w stages kc-chunk w x all 256 rows (slot = kc*256+row)
#pragma unroll
        for (int i = 0; i < 4; i++) {
            const int rr    = i * 64;                // + lane via DMA
            const int sbase = w * 256 + rr;
            GLOAD16(W2 + (size_t)(rr + lane) * K1 + k0 + w * 8, &As[sbase * 8]);
        }
        // B: bilinear sample of 8 channels (R9-verbatim per-pixel math)
        {
            const int o_dy = (g * 9 + kk) * 2, o_dx = o_dy + 1;
            const float dy = fmaf(offset_w[o_dy * 2], s01.x, offset_w[o_dy * 2 + 1] * s01.y);
            const float dx = fmaf(offset_w[o_dx * 2], s01.x, offset_w[o_dx * 2 + 1] * s01.y);
            const float py = (float)(y + kk / 3 - 1) + dy;
            const float px = (float)(x + kk % 3 - 1) + dx;
            const float y0f = floorf(py), x0f = floorf(px);
            const float wy = py - y0f, wx = px - x0f;
            const int y0 = (int)y0f, x0 = (int)x0f;
            const int y1 = y0 + 1, x1 = x0 + 1;
            const bool vy0 = (y0 >= 0) && (y0 < HH), vy1 = (y1 >= 0) && (y1 < HH);
            const bool vx0 = (x0 >= 0) && (x0 < WW), vx1 = (x1 >= 0) && (x1 < WW);
            const int y0c = min(max(y0, 0), HH - 1), y1c = min(max(y1, 0), HH - 1);
            const int x0c = min(max(x0, 0), WW - 1), x1c = min(max(x1, 0), WW - 1);
            const float w00 = (vy0 && vx0) ? (1.f - wy) * (1.f - wx) : 0.f;
            const float w01 = (vy0 && vx1) ? (1.f - wy) * wx         : 0.f;
            const float w10 = (vy1 && vx0) ? wy * (1.f - wx)         : 0.f;
            const float w11 = (vy1 && vx1) ? wy * wx                 : 0.f;
            const int ch = g * 64 + kc * 8;
            const short8v v00 = *(const short8v*)(tb + (size_t)(y0c * WW + x0c) * CC + ch);
            const short8v v01 = *(const short8v*)(tb + (size_t)(y0c * WW + x1c) * CC + ch);
            const short8v v10 = *(const short8v*)(tb + (size_t)(y1c * WW + x0c) * CC + ch);
            const short8v v11 = *(const short8v*)(tb + (size_t)(y1c * WW + x1c) * CC + ch);
            short8v r;
#pragma unroll
            for (int e = 0; e < 8; e++) {
                float val = w00 * bf2f((unsigned short)v00[e]);
                val = fmaf(w01, bf2f((unsigned short)v01[e]), val);
                val = fmaf(w10, bf2f((unsigned short)v10[e]), val);
                val = fmaf(w11, bf2f((unsigned short)v11[e]), val);
                r[e] = (short)f2bf(val);
            }
            *(short8v*)&Bs[(pr * 9 + kc) * 8] = r;
        }
        __syncthreads();
#pragma unroll
        for (int ks = 0; ks < 2; ks++) {
            short8v a[4], bf[2];
#pragma unroll
            for (int i = 0; i < 4; i++)
                a[i] = *(const short8v*)&As[(((ks * 4 + quad) * 256) + wm * 64 + i * 16 + r15) * 8];
#pragma unroll
            for (int j = 0; j < 2; j++)
                bf[j] = *(const short8v*)&Bs[((wn * 32 + j * 16 + r15) * 9 + ks * 4 + quad) * 8];
#pragma unroll
            for (int i = 0; i < 4; i++)
#pragma unroll
                for (int j = 0; j < 2; j++)
                    acc[i][j] = __builtin_amdgcn_mfma_f32_16x16x32_bf16(a[i], bf[j], acc[i][j], 0, 0, 0);
        }
        __syncthreads();
    }
    // epilogue: fp32 partial, no relu, c-major pta[c][n] (4-line stores)
    float* pta = kh ? pta1 : pta0;
#pragma unroll
    for (int i = 0; i < 4; i++) {
        const int m = wm * 64 + i * 16 + quad * 4;
#pragma unroll
        for (int j = 0; j < 2; j++) {
            const int n = n0 + wn * 32 + j * 16 + r15;
            pta[(size_t)(m + 0) * NTOT + n] = acc[i][j][0];
            pta[(size_t)(m + 1) * NTOT + n] = acc[i][j][1];
            pta[(size_t)(m + 2) * NTOT + n] = acc[i][j][2];
            pta[(size_t)(m + 3) * NTOT + n] = acc[i][j][3];
        }
    }
}

// ---- heads2: cls/bbox from relu(pta0+pta1), c-major pta, coalesced ---------
// Block = 64 pixels x 4 c-quarters; loads coalesced across n for fixed c;
// relu per-channel BEFORE the (linear) cross-quarter sum -> order-safe.
__global__ __launch_bounds__(256) void heads2_kernel(
    const float* __restrict__ pta0, const float* __restrict__ pta1,
    const float* __restrict__ cls_w, const float* __restrict__ cls_b,
    const float* __restrict__ bbox_w, const float* __restrict__ bbox_b,
    float* __restrict__ out)
{
    __shared__ float sm[4][64][5];
    const int nl = threadIdx.x & 63, qc = threadIdx.x >> 6;
    const int n = blockIdx.x * 64 + nl;
    const int b = n / HWP, p = n - b * HWP;
    float ac = 0.f, a0 = 0.f, a1 = 0.f, a2 = 0.f, a3 = 0.f;
#pragma unroll 8
    for (int i = 0; i < 64; i++) {
        const int c = qc * 64 + i;
        const size_t idx = (size_t)c * NTOT + n;
        const float fv = fmaxf(pta0[idx] + pta1[idx], 0.f);
        ac = fmaf(cls_w[c], fv, ac);
        a0 = fmaf(bbox_w[c], fv, a0);
        a1 = fmaf(bbox_w[CC + c], fv, a1);
        a2 = fmaf(bbox_w[2 * CC + c], fv, a2);
        a3 = fmaf(bbox_w[3 * CC + c], fv, a3);
    }
    sm[qc][nl][0] = ac; sm[qc][nl][1] = a0; sm[qc][nl][2] = a1;
    sm[qc][nl][3] = a2; sm[qc][nl][4] = a3;
    __syncthreads();
    if (qc == 0) {
        ac = sm[0][nl][0] + sm[1][nl][0] + sm[2][nl][0] + sm[3][nl][0];
        a0 = sm[0][nl][1] + sm[1][nl][1] + sm[2][nl][1] + sm[3][nl][1];
        a1 = sm[0][nl][2] + sm[1][nl][2] + sm[2][nl][2] + sm[3][nl][2];
        a2 = sm[0][nl][3] + sm[1][nl][3] + sm[2][nl][3] + sm[3][nl][3];
        a3 = sm[0][nl][4] + sm[1][nl][4] + sm[2][nl][4] + sm[3][nl][4];
        out[OUT_LOGITS + n] = ac + cls_b[0];
        out[OUT_BBOX + (b * 4 + 0) * HWP + p] = a0 + bbox_b[0];
        out[OUT_BBOX + (b * 4 + 1) * HWP + p] = a1 + bbox_b[1];
        out[OUT_BBOX + (b * 4 + 2) * HWP + p] = a2 + bbox_b[2];
        out[OUT_BBOX + (b * 4 + 3) * HWP + p] = a3 + bbox_b[3];
    }
}

// ----------------------------------------------------------------------------
extern "C" void kernel_launch(void* const* d_in, const int* in_sizes, int n_in,
                              void* d_out, int out_size, void* d_ws, size_t ws_size,
                              hipStream_t stream)
{
    const float* feature  = (const float*)d_in[0];
    const float* conv_w   = (const float*)d_in[1];
    const float* conv_b   = (const float*)d_in[2];
    const float* loc_w    = (const float*)d_in[3];
    const float* loc_b    = (const float*)d_in[4];
    const float* shape_w  = (const float*)d_in[5];
    const float* shape_b  = (const float*)d_in[6];
    const float* offset_w = (const float*)d_in[7];
    const float* adapt_w  = (const float*)d_in[8];
    const float* cls_w    = (const float*)d_in[9];
    const float* cls_b    = (const float*)d_in[10];
    const float* bbox_w   = (const float*)d_in[11];
    const float* bbox_b   = (const float*)d_in[12];
    float* out = (float*)d_out;

    // workspace partition (~59 MB, R9-proven)
    float*          s0s1 = (float*)d_ws;                           // NTOT float2
    unsigned short* tcf  = (unsigned short*)(s0s1 + 2 * NTOT);     // NTOT*CC bf16
    unsigned short* fcf  = tcf + (size_t)NTOT * CC;                // NTOT*CC bf16
    unsigned short* W1   = fcf + (size_t)NTOT * CC;                // CC*K1 bf16
    unsigned short* W2   = W1 + (size_t)CC * K1;                   // CC*K1 bf16
    unsigned short* zp   = W2 + (size_t)CC * K1;                   // 1024 zeros
    float*          pta0 = (float*)(zp + 1024);                    // CC x NTOT fp32 (c-major)
    float*          pta1 = pta0 + (size_t)NTOT * CC;               // CC x NTOT fp32 (c-major)

    prep_kernel<<<(CC * K1 + 255) / 256, 256, 0, stream>>>(conv_w, adapt_w, W1, W2, zp);
    transpose_kernel<<<dim3(HWP / 64, 4, BB), 256, 0, stream>>>(feature, fcf);
    gemm1_kernel<<<dim3(NTOT / 64, 2), 512, 0, stream>>>(W1, fcf, conv_b, zp, tcf);
    heads1_kernel<<<dim3(NTOT / 4), 256, 0, stream>>>(
        tcf, loc_w, loc_b, shape_w, shape_b, out, s0s1);
    gemm2_fused_kernel<<<dim3(NTOT / 64, 2), 512, 0, stream>>>(
        W2, tcf, s0s1, offset_w, pta0, pta1);
    heads2_kernel<<<dim3(NTOT / 64), 256, 0, stream>>>(
        pta0, pta1, cls_w, cls_b, bbox_w, bbox_b, out);
}

// Round 15
// 209.731 us; speedup vs baseline: 1.9889x; 1.2902x over previous
//
#include <hip/hip_runtime.h>
#include <hip/hip_bf16.h>

// Problem constants
#define BB 2
#define CC 256
#define HH 96
#define WW 96
#define HWP (HH*WW)        // 9216
#define NTOT (BB*HWP)      // 18432 flattened (b,p)
#define K1 2304            // 256*9, GEMM K for both convs
#define NKT 36             // K1/64 k-steps
#define KHS 18             // k-steps per split-K half (gemm2)

// d_out layout: logits[2,1,96,96], bbox[2,4,96,96], shape[2,2,96,96], loc[2,1,96,96]
#define OUT_LOGITS 0
#define OUT_BBOX   (2*1*HWP)
#define OUT_SHAPE  (OUT_BBOX + 2*4*HWP)
#define OUT_LOC    (OUT_SHAPE + 2*2*HWP)

typedef __attribute__((ext_vector_type(8))) short short8v;   // 8 bf16 (4 VGPRs)
typedef __attribute__((ext_vector_type(4))) float f32x4;

typedef const __attribute__((address_space(1))) void* gptr_t;
typedef __attribute__((address_space(3))) void* lptr_t;
#define GLOAD16(g, l) __builtin_amdgcn_global_load_lds((gptr_t)(g), (lptr_t)(l), 16, 0, 0)

// XCD-aware swizzle: 288 n-blocks, 8 XCDs -> contiguous 1.18 MB slab per XCD.
// [R12 measured: FETCH 56 -> 11.7 MB. Keeper.]
__device__ __forceinline__ int xcd_swizzle288(int bx) {
    return (bx & 7) * 36 + (bx >> 3);
}

__device__ __forceinline__ float bf2f(unsigned short u) {
    return __uint_as_float(((unsigned)u) << 16);
}
__device__ __forceinline__ unsigned short f2bf(float f) {
    unsigned u = __float_as_uint(f);
    u += 0x7FFFu + ((u >> 16) & 1u);           // round-to-nearest-even
    return (unsigned short)(u >> 16);
}

// ------- prep: weights -> bf16 PRE-SWIZZLED A panels + zero page ------------
// W1p[((cb*36+kt)*1024 + kc*128+row)*8 + e] = W1[cb*128+row][kt*64+kc*8+e]
// W2p[((kt)*2048      + kc*256+row)*8 + e] = W2[row]       [kt*64+kc*8+e]
// (k = kk*256+ci order). A-staging then reads CONTIGUOUS 1KB per wave-instr
// instead of 64-line gathers (R14 lesson: TA serialization was the binder).
__global__ __launch_bounds__(256) void prep_kernel(
    const float* __restrict__ conv_w, const float* __restrict__ adapt_w,
    unsigned short* __restrict__ W1p, unsigned short* __restrict__ W2p,
    unsigned short* __restrict__ zp)
{
    const int t = blockIdx.x * 256 + threadIdx.x;
    if (t < 1024) zp[t] = 0;                    // zero page (ws is re-poisoned!)
    if (t < CC * K1) {
        const int e = t & 7;
        {   // W1p
            const int s  = (t >> 3) & 1023;
            const int r  = t >> 13;             // cb*36+kt, [0,72)
            const int kt = r % 36, cb = r / 36;
            const int row = s & 127, kc = s >> 7;
            const int co = cb * 128 + row;
            const int k  = kt * 64 + kc * 8 + e;
            const int kk = k >> 8, ci = k & 255;
            W1p[t] = f2bf(conv_w[co * K1 + ci * 9 + kk]);
        }
        {   // W2p
            const int s  = (t >> 3) & 2047;
            const int kt = t >> 14;             // [0,36)
            const int row = s & 255, kc = s >> 8;
            const int k  = kt * 64 + kc * 8 + e;
            const int kk = k >> 8, ci = k & 255;
            W2p[t] = f2bf(adapt_w[row * K1 + ci * 9 + kk]);
        }
    }
}

// ------------- transpose feature [b][c][p] fp32 -> f_cf [b][p][c] bf16 ------
__global__ __launch_bounds__(256) void transpose_kernel(
    const float* __restrict__ f, unsigned short* __restrict__ fcf)
{
    __shared__ unsigned short tile[64][66];     // +2 pad: conflict-free col reads
    const int p0 = blockIdx.x * 64;
    const int cc = blockIdx.y;
    const int b  = blockIdx.z;
    const int tx = threadIdx.x & 63, ty = threadIdx.x >> 6;
#pragma unroll
    for (int ii = 0; ii < 16; ii++) {
        const int cl = ii * 4 + ty;
        tile[cl][tx] = f2bf(f[((size_t)b * CC + cc * 64 + cl) * HWP + p0 + tx]);
    }
    __syncthreads();
#pragma unroll
    for (int ii = 0; ii < 16; ii++) {
        const int pl = ii * 4 + ty;
        fcf[((size_t)(b * HWP + p0 + pl)) * CC + cc * 64 + tx] = tile[tx][pl];
    }
}

// --------- GEMM1: t = relu(W1 x im2col + bias), 512 thr / 8 waves -----------
// M=128 x N=64, BK=64. A: contiguous GLOAD16 from pre-swizzled W1p panel.
// B: (pr,kc) coalesced short8 loads (16-line/wave) + ds_write into
// XOR-swizzled row-major Bs: slot = pr*8 + (kc^(pr&7)) -> conflict-free R/W.
__global__ __launch_bounds__(512, 6) void gemm1_kernel(
    const unsigned short* __restrict__ W1p, const unsigned short* __restrict__ fcf,
    const float* __restrict__ bias, const unsigned short* __restrict__ zp,
    unsigned short* __restrict__ tcf)
{
    __shared__ short As[8192];                  // 128 rows x 64 k = 16 KB
    __shared__ short Bs[4096];                  // 64 rows x 8 chunks, XOR = 8 KB
    const int tid  = threadIdx.x;
    const int lane = tid & 63, w = tid >> 6;    // w in [0,8)
    const int quad = lane >> 4, r15 = lane & 15;
    const int n0  = xcd_swizzle288(blockIdx.x) * 64;
    const int cb  = blockIdx.y;
    const int co0 = cb * 128;
    const int wm = w & 3, wn = w >> 2;          // co-quarter (32 rows), n-half

    // B staging geometry: thread -> (pixel pr, 8-ch chunk kc)
    const int pr = tid >> 3, kc = tid & 7;
    const int xsw = (pr * 8 + (kc ^ (pr & 7))) * 8;   // Bs write slot (shorts)
    const int nb = n0 + pr;
    const int b  = nb / HWP;
    const int p  = nb - b * HWP;
    const int y = p / WW, x = p % WW;
    const unsigned short* fb = fcf + (size_t)b * HWP * CC;

    f32x4 acc[2][2];
#pragma unroll
    for (int i = 0; i < 2; i++)
#pragma unroll
        for (int j = 0; j < 2; j++) acc[i][j] = (f32x4){0.f, 0.f, 0.f, 0.f};

    for (int kt = 0; kt < NKT; kt++) {
        // A: contiguous panel slice (slot = kc*128+row pre-baked in W1p)
        const unsigned short* w1panel = W1p + ((size_t)(cb * 36 + kt) * 1024) * 8;
#pragma unroll
        for (int i = 0; i < 2; i++) {
            const int s0c = w * 128 + i * 64;   // + lane (both src and dst)
            GLOAD16(w1panel + (size_t)(s0c + lane) * 8, &As[s0c * 8]);
        }
        // B: coalesced row-chunk load (implicit im2col) + XOR ds_write
        {
            const int kk  = kt >> 2;
            const int ci0 = (kt & 3) * 64;
            const int yy = y + kk / 3 - 1, xx = x + kk % 3 - 1;
            const bool ok = (yy >= 0) && (yy < HH) && (xx >= 0) && (xx < WW);
            const unsigned short* src = ok
                ? fb + (size_t)(yy * WW + xx) * CC + ci0 + kc * 8
                : zp;
            *(short8v*)&Bs[xsw] = *(const short8v*)src;
        }
        __syncthreads();
#pragma unroll
        for (int ks = 0; ks < 2; ks++) {
            short8v a[2], bf[2];
            const int kchunk = ks * 4 + quad;
#pragma unroll
            for (int i = 0; i < 2; i++)
                a[i] = *(const short8v*)&As[((kchunk * 128) + wm * 32 + i * 16 + r15) * 8];
#pragma unroll
            for (int j = 0; j < 2; j++) {
                const int row = wn * 32 + j * 16 + r15;
                bf[j] = *(const short8v*)&Bs[(row * 8 + (kchunk ^ (row & 7))) * 8];
            }
#pragma unroll
            for (int i = 0; i < 2; i++)
#pragma unroll
                for (int j = 0; j < 2; j++)
                    acc[i][j] = __builtin_amdgcn_mfma_f32_16x16x32_bf16(a[i], bf[j], acc[i][j], 0, 0, 0);
        }
        __syncthreads();
    }
    // epilogue: bias + relu -> t_cf[n][c] bf16 (C/D map: col=lane&15, row=quad*4+reg)
#pragma unroll
    for (int i = 0; i < 2; i++) {
        const int m = co0 + wm * 32 + i * 16 + quad * 4;
        const float b0 = bias[m], b1 = bias[m + 1], b2 = bias[m + 2], b3 = bias[m + 3];
#pragma unroll
        for (int j = 0; j < 2; j++) {
            const int n = n0 + wn * 32 + j * 16 + r15;
            ushort4 st;
            st.x = f2bf(fmaxf(acc[i][j][0] + b0, 0.f));
            st.y = f2bf(fmaxf(acc[i][j][1] + b1, 0.f));
            st.z = f2bf(fmaxf(acc[i][j][2] + b2, 0.f));
            st.w = f2bf(fmaxf(acc[i][j][3] + b3, 0.f));
            *(ushort4*)(tcf + (size_t)n * CC + m) = st;
        }
    }
}

// ---- heads1: wave-per-pixel, lane = 4-channel chunk (coalesced row read) ---
__global__ __launch_bounds__(256) void heads1_kernel(
    const unsigned short* __restrict__ tcf,
    const float* __restrict__ loc_w, const float* __restrict__ loc_b,
    const float* __restrict__ shape_w, const float* __restrict__ shape_b,
    float* __restrict__ out, float* __restrict__ s0s1)
{
    const int lane = threadIdx.x & 63, wv = threadIdx.x >> 6;
    const int n = blockIdx.x * 4 + wv;
    const int b = n / HWP, p = n - b * HWP;
    const int c = lane * 4;
    const ushort4 v = *(const ushort4*)(tcf + (size_t)n * CC + c);
    const float f0 = bf2f(v.x), f1 = bf2f(v.y), f2 = bf2f(v.z), f3 = bf2f(v.w);
    float aloc, s0, s1;
    aloc = loc_w[c] * f0;           aloc = fmaf(loc_w[c+1], f1, aloc);
    aloc = fmaf(loc_w[c+2], f2, aloc); aloc = fmaf(loc_w[c+3], f3, aloc);
    s0 = shape_w[c] * f0;           s0 = fmaf(shape_w[c+1], f1, s0);
    s0 = fmaf(shape_w[c+2], f2, s0);   s0 = fmaf(shape_w[c+3], f3, s0);
    s1 = shape_w[CC+c] * f0;        s1 = fmaf(shape_w[CC+c+1], f1, s1);
    s1 = fmaf(shape_w[CC+c+2], f2, s1); s1 = fmaf(shape_w[CC+c+3], f3, s1);
#pragma unroll
    for (int off = 32; off; off >>= 1) {
        aloc += __shfl_xor(aloc, off);
        s0   += __shfl_xor(s0, off);
        s1   += __shfl_xor(s1, off);
    }
    if (lane == 0) {
        const float l = aloc + loc_b[0], a = s0 + shape_b[0], cc2 = s1 + shape_b[1];
        out[OUT_LOC + n] = l;
        out[OUT_SHAPE + (b * 2 + 0) * HWP + p] = a;
        out[OUT_SHAPE + (b * 2 + 1) * HWP + p] = cc2;
        *(float2*)&s0s1[2 * n] = make_float2(a, cc2);
    }
}

// ---- fused GEMM2, split-K=2, M=256 x N=64, 512 thr / 8 waves ---------------
// A: contiguous GLOAD16 from pre-swizzled W2p panel. Sampler (R9-verbatim
// per-pixel math) writes XOR-swizzled Bs. fp32 partials c-major (R14).
__global__ __launch_bounds__(512, 6) void gemm2_fused_kernel(
    const unsigned short* __restrict__ W2p, const unsigned short* __restrict__ tcf,
    const float* __restrict__ s0s1, const float* __restrict__ offset_w,
    float* __restrict__ pta0, float* __restrict__ pta1)
{
    __shared__ short As[16384];                 // 8 kc-chunks x 256 rows = 32 KB
    __shared__ short Bs[4096];                  // 64 rows x 8 chunks, XOR = 8 KB
    const int tid  = threadIdx.x;
    const int lane = tid & 63, w = tid >> 6;    // w in [0,8)
    const int quad = lane >> 4, r15 = lane & 15;
    const int n0  = xcd_swizzle288(blockIdx.x) * 64;
    const int kh  = blockIdx.y;                 // split-K half
    const int b   = n0 / HWP;                   // whole block in one batch
    const unsigned short* tb = tcf + (size_t)b * HWP * CC;
    const int wm = w & 3, wn = w >> 2;          // co-quarter, n-half

    // sampler mapping: thread -> pixel pr, 8-ch chunk kc (one pixel/thread)
    const int pr = tid >> 3, kc = tid & 7;
    const int xsw = (pr * 8 + (kc ^ (pr & 7))) * 8;   // Bs write slot (shorts)
    const int nb = n0 + pr;
    const int p  = nb - b * HWP;
    const int y = p / WW, x = p % WW;
    const float2 s01 = *(const float2*)&s0s1[2 * nb];

    f32x4 acc[4][2];
#pragma unroll
    for (int i = 0; i < 4; i++)
#pragma unroll
        for (int j = 0; j < 2; j++) acc[i][j] = (f32x4){0.f, 0.f, 0.f, 0.f};

    for (int kt = kh * KHS; kt < kh * KHS + KHS; kt++) {
        const int kk = kt >> 2, g = kt & 3;
        // A: contiguous panel slice (slot = kc*256+row pre-baked in W2p)
        const unsigned short* w2panel = W2p + ((size_t)kt * 2048) * 8;
#pragma unroll
        for (int i = 0; i < 4; i++) {
            const int s0c = w * 256 + i * 64;   // + lane (both src and dst)
            GLOAD16(w2panel + (size_t)(s0c + lane) * 8, &As[s0c * 8]);
        }
        // B: bilinear sample of 8 channels (R9-verbatim per-pixel math)
        {
            const int o_dy = (g * 9 + kk) * 2, o_dx = o_dy + 1;
            const float dy = fmaf(offset_w[o_dy * 2], s01.x, offset_w[o_dy * 2 + 1] * s01.y);
            const float dx = fmaf(offset_w[o_dx * 2], s01.x, offset_w[o_dx * 2 + 1] * s01.y);
            const float py = (float)(y + kk / 3 - 1) + dy;
            const float px = (float)(x + kk % 3 - 1) + dx;
            const float y0f = floorf(py), x0f = floorf(px);
            const float wy = py - y0f, wx = px - x0f;
            const int y0 = (int)y0f, x0 = (int)x0f;
            const int y1 = y0 + 1, x1 = x0 + 1;
            const bool vy0 = (y0 >= 0) && (y0 < HH), vy1 = (y1 >= 0) && (y1 < HH);
            const bool vx0 = (x0 >= 0) && (x0 < WW), vx1 = (x1 >= 0) && (x1 < WW);
            const int y0c = min(max(y0, 0), HH - 1), y1c = min(max(y1, 0), HH - 1);
            const int x0c = min(max(x0, 0), WW - 1), x1c = min(max(x1, 0), WW - 1);
            const float w00 = (vy0 && vx0) ? (1.f - wy) * (1.f - wx) : 0.f;
            const float w01 = (vy0 && vx1) ? (1.f - wy) * wx         : 0.f;
            const float w10 = (vy1 && vx0) ? wy * (1.f - wx)         : 0.f;
            const float w11 = (vy1 && vx1) ? wy * wx                 : 0.f;
            const int ch = g * 64 + kc * 8;
            const short8v v00 = *(const short8v*)(tb + (size_t)(y0c * WW + x0c) * CC + ch);
            const short8v v01 = *(const short8v*)(tb + (size_t)(y0c * WW + x1c) * CC + ch);
            const short8v v10 = *(const short8v*)(tb + (size_t)(y1c * WW + x0c) * CC + ch);
            const short8v v11 = *(const short8v*)(tb + (size_t)(y1c * WW + x1c) * CC + ch);
            short8v r;
#pragma unroll
            for (int e = 0; e < 8; e++) {
                float val = w00 * bf2f((unsigned short)v00[e]);
                val = fmaf(w01, bf2f((unsigned short)v01[e]), val);
                val = fmaf(w10, bf2f((unsigned short)v10[e]), val);
                val = fmaf(w11, bf2f((unsigned short)v11[e]), val);
                r[e] = (short)f2bf(val);
            }
            *(short8v*)&Bs[xsw] = r;
        }
        __syncthreads();
#pragma unroll
        for (int ks = 0; ks < 2; ks++) {
            short8v a[4], bf[2];
            const int kchunk = ks * 4 + quad;
#pragma unroll
            for (int i = 0; i < 4; i++)
                a[i] = *(const short8v*)&As[((kchunk * 256) + wm * 64 + i * 16 + r15) * 8];
#pragma unroll
            for (int j = 0; j < 2; j++) {
                const int row = wn * 32 + j * 16 + r15;
                bf[j] = *(const short8v*)&Bs[(row * 8 + (kchunk ^ (row & 7))) * 8];
            }
#pragma unroll
            for (int i = 0; i < 4; i++)
#pragma unroll
                for (int j = 0; j < 2; j++)
                    acc[i][j] = __builtin_amdgcn_mfma_f32_16x16x32_bf16(a[i], bf[j], acc[i][j], 0, 0, 0);
        }
        __syncthreads();
    }
    // epilogue: fp32 partial, no relu, c-major pta[c][n] (R14)
    float* pta = kh ? pta1 : pta0;
#pragma unroll
    for (int i = 0; i < 4; i++) {
        const int m = wm * 64 + i * 16 + quad * 4;
#pragma unroll
        for (int j = 0; j < 2; j++) {
            const int n = n0 + wn * 32 + j * 16 + r15;
            pta[(size_t)(m + 0) * NTOT + n] = acc[i][j][0];
            pta[(size_t)(m + 1) * NTOT + n] = acc[i][j][1];
            pta[(size_t)(m + 2) * NTOT + n] = acc[i][j][2];
            pta[(size_t)(m + 3) * NTOT + n] = acc[i][j][3];
        }
    }
}

// ---- heads2: cls/bbox from relu(pta0+pta1), c-major pta, coalesced ---------
__global__ __launch_bounds__(256) void heads2_kernel(
    const float* __restrict__ pta0, const float* __restrict__ pta1,
    const float* __restrict__ cls_w, const float* __restrict__ cls_b,
    const float* __restrict__ bbox_w, const float* __restrict__ bbox_b,
    float* __restrict__ out)
{
    __shared__ float sm[4][64][5];
    const int nl = threadIdx.x & 63, qc = threadIdx.x >> 6;
    const int n = blockIdx.x * 64 + nl;
    const int b = n / HWP, p = n - b * HWP;
    float ac = 0.f, a0 = 0.f, a1 = 0.f, a2 = 0.f, a3 = 0.f;
#pragma unroll 8
    for (int i = 0; i < 64; i++) {
        const int c = qc * 64 + i;
        const size_t idx = (size_t)c * NTOT + n;
        const float fv = fmaxf(pta0[idx] + pta1[idx], 0.f);
        ac = fmaf(cls_w[c], fv, ac);
        a0 = fmaf(bbox_w[c], fv, a0);
        a1 = fmaf(bbox_w[CC + c], fv, a1);
        a2 = fmaf(bbox_w[2 * CC + c], fv, a2);
        a3 = fmaf(bbox_w[3 * CC + c], fv, a3);
    }
    sm[qc][nl][0] = ac; sm[qc][nl][1] = a0; sm[qc][nl][2] = a1;
    sm[qc][nl][3] = a2; sm[qc][nl][4] = a3;
    __syncthreads();
    if (qc == 0) {
        ac = sm[0][nl][0] + sm[1][nl][0] + sm[2][nl][0] + sm[3][nl][0];
        a0 = sm[0][nl][1] + sm[1][nl][1] + sm[2][nl][1] + sm[3][nl][1];
        a1 = sm[0][nl][2] + sm[1][nl][2] + sm[2][nl][2] + sm[3][nl][2];
        a2 = sm[0][nl][3] + sm[1][nl][3] + sm[2][nl][3] + sm[3][nl][3];
        a3 = sm[0][nl][4] + sm[1][nl][4] + sm[2][nl][4] + sm[3][nl][4];
        out[OUT_LOGITS + n] = ac + cls_b[0];
        out[OUT_BBOX + (b * 4 + 0) * HWP + p] = a0 + bbox_b[0];
        out[OUT_BBOX + (b * 4 + 1) * HWP + p] = a1 + bbox_b[1];
        out[OUT_BBOX + (b * 4 + 2) * HWP + p] = a2 + bbox_b[2];
        out[OUT_BBOX + (b * 4 + 3) * HWP + p] = a3 + bbox_b[3];
    }
}

// ----------------------------------------------------------------------------
extern "C" void kernel_launch(void* const* d_in, const int* in_sizes, int n_in,
                              void* d_out, int out_size, void* d_ws, size_t ws_size,
                              hipStream_t stream)
{
    const float* feature  = (const float*)d_in[0];
    const float* conv_w   = (const float*)d_in[1];
    const float* conv_b   = (const float*)d_in[2];
    const float* loc_w    = (const float*)d_in[3];
    const float* loc_b    = (const float*)d_in[4];
    const float* shape_w  = (const float*)d_in[5];
    const float* shape_b  = (const float*)d_in[6];
    const float* offset_w = (const float*)d_in[7];
    const float* adapt_w  = (const float*)d_in[8];
    const float* cls_w    = (const float*)d_in[9];
    const float* cls_b    = (const float*)d_in[10];
    const float* bbox_w   = (const float*)d_in[11];
    const float* bbox_b   = (const float*)d_in[12];
    float* out = (float*)d_out;

    // workspace partition (~59 MB, R9-proven)
    float*          s0s1 = (float*)d_ws;                           // NTOT float2
    unsigned short* tcf  = (unsigned short*)(s0s1 + 2 * NTOT);     // NTOT*CC bf16
    unsigned short* fcf  = tcf + (size_t)NTOT * CC;                // NTOT*CC bf16
    unsigned short* W1p  = fcf + (size_t)NTOT * CC;                // CC*K1 bf16 (panels)
    unsigned short* W2p  = W1p + (size_t)CC * K1;                  // CC*K1 bf16 (panels)
    unsigned short* zp   = W2p + (size_t)CC * K1;                  // 1024 zeros
    float*          pta0 = (float*)(zp + 1024);                    // CC x NTOT fp32 (c-major)
    float*          pta1 = pta0 + (size_t)NTOT * CC;               // CC x NTOT fp32 (c-major)

    prep_kernel<<<(CC * K1 + 255) / 256, 256, 0, stream>>>(conv_w, adapt_w, W1p, W2p, zp);
    transpose_kernel<<<dim3(HWP / 64, 4, BB), 256, 0, stream>>>(feature, fcf);
    gemm1_kernel<<<dim3(NTOT / 64, 2), 512, 0, stream>>>(W1p, fcf, conv_b, zp, tcf);
    heads1_kernel<<<dim3(NTOT / 4), 256, 0, stream>>>(
        tcf, loc_w, loc_b, shape_w, shape_b, out, s0s1);
    gemm2_fused_kernel<<<dim3(NTOT / 64, 2), 512, 0, stream>>>(
        W2p, tcf, s0s1, offset_w, pta0, pta1);
    heads2_kernel<<<dim3(NTOT / 64), 256, 0, stream>>>(
        pta0, pta1, cls_w, cls_b, bbox_w, bbox_b, out);
}